// Round 1
// baseline (1357.137 us; speedup 1.0000x reference)
//
#include <hip/hip_runtime.h>
#include <hip/hip_bf16.h>
#include <math.h>

#define N_NODES 20000
#define N_EDGES 256000
#define NHEADS 8
#define DIN_ 256
#define DH_ 32
#define PRED_ 32
#define REL_ 16

// ---------------- small setup kernels ----------------

// saTab[l][r][h] = sum_p rel_emb[r,p] * sa_We[l,p,h]   (2*16*8 = 256)
// epTab[r][c]    = sum_p rel_emb[r,p] * We_gt[p,c]     (16*256)
__global__ void k_tables(const float* __restrict__ rel_emb,
                         const float* __restrict__ sa_We,
                         const float* __restrict__ We_gt,
                         float* __restrict__ saTab, float* __restrict__ epTab) {
  int t = threadIdx.x;
  {
    int l = t >> 7, r = (t >> 3) & 15, h = t & 7;
    float acc = 0.f;
    for (int p = 0; p < 32; ++p)
      acc += rel_emb[r * 32 + p] * sa_We[l * 256 + p * 8 + h];
    saTab[t] = acc;
  }
  for (int r = 0; r < 16; ++r) {
    float acc = 0.f;
    for (int p = 0; p < 32; ++p)
      acc += rel_emb[r * 32 + p] * We_gt[p * 256 + t];
    epTab[r * 256 + t] = acc;
  }
}

__global__ void k_hist(const int* __restrict__ e_dst, int* __restrict__ deg) {
  int e = blockIdx.x * 256 + threadIdx.x;
  if (e < N_EDGES) atomicAdd(&deg[e_dst[e]], 1);
}

// single-block exclusive scan of deg[N] -> rowPtr[N+1], cursor copy
__global__ void k_scan(const int* __restrict__ deg, int* __restrict__ rowPtr,
                       int* __restrict__ cursor) {
  const int CH = (N_NODES + 255) / 256;  // 79
  int t = threadIdx.x;
  int b0 = t * CH, b1 = min(b0 + CH, N_NODES);
  int s = 0;
  for (int i = b0; i < b1; ++i) s += deg[i];
  __shared__ int part[256];
  part[t] = s;
  __syncthreads();
  for (int off = 1; off < 256; off <<= 1) {
    int add = (t >= off) ? part[t - off] : 0;
    __syncthreads();
    part[t] += add;
    __syncthreads();
  }
  int run = (t == 0) ? 0 : part[t - 1];
  for (int i = b0; i < b1; ++i) {
    rowPtr[i] = run;
    cursor[i] = run;
    run += deg[i];
  }
  if (t == 0) rowPtr[N_NODES] = part[255];
}

__global__ void k_fill(const int* __restrict__ e_dst, const int* __restrict__ e_src,
                       const int* __restrict__ e_type, int* __restrict__ cursor,
                       int* __restrict__ csrSrc, int* __restrict__ csrType) {
  int e = blockIdx.x * 256 + threadIdx.x;
  if (e >= N_EDGES) return;
  int d = e_dst[e];
  int pos = atomicAdd(&cursor[d], 1);
  csrSrc[pos] = e_src[e];
  csrType[pos] = e_type[e];
}

// ---------------- structural channel ----------------

// fused per-head scoring MLP: h0[n,h] = sum_k relu(x.Ws1[h,:,k]+bs1) * Ws2[h,k] + bs2
// block = 16 nodes, 256 threads: thread -> (node = t&15, kgroup = t>>4 covering 8 k)
__global__ __launch_bounds__(256) void k_mlp(const float* __restrict__ X,
                                             const float* __restrict__ Ws1,
                                             const float* __restrict__ bs1,
                                             const float* __restrict__ Ws2,
                                             const float* __restrict__ bs2,
                                             float* __restrict__ h0) {
  __shared__ float xs[16][260];
  __shared__ float red[16][17];
  int tid = threadIdx.x;
  int base = blockIdx.x * 16;
  const float4* X4 = (const float4*)(X + (size_t)base * 256);
  #pragma unroll
  for (int r = 0; r < 4; ++r) {
    int fi = tid + r * 256;
    int nd = fi >> 6, dq = fi & 63;
    *(float4*)&xs[nd][dq * 4] = X4[nd * 64 + dq];
  }
  __syncthreads();
  int node = tid & 15, kg = tid >> 4;
  int k0 = kg * 8;
  for (int h = 0; h < 8; ++h) {
    const float* wb = Ws1 + h * 32768 + k0;
    float acc[8];
    #pragma unroll
    for (int j = 0; j < 8; ++j) acc[j] = 0.f;
    #pragma unroll 4
    for (int d = 0; d < 256; ++d) {
      float xv = xs[node][d];
      float4 wa = *(const float4*)(wb + d * 128);
      float4 wc = *(const float4*)(wb + d * 128 + 4);
      acc[0] += xv * wa.x; acc[1] += xv * wa.y; acc[2] += xv * wa.z; acc[3] += xv * wa.w;
      acc[4] += xv * wc.x; acc[5] += xv * wc.y; acc[6] += xv * wc.z; acc[7] += xv * wc.w;
    }
    float hsum = 0.f;
    #pragma unroll
    for (int j = 0; j < 8; ++j) {
      float tv = acc[j] + bs1[h * 128 + k0 + j];
      tv = fmaxf(tv, 0.f);
      hsum += tv * Ws2[h * 128 + k0 + j];
    }
    red[kg][node] = hsum;
    __syncthreads();
    if (kg == 0) {
      float sacc = 0.f;
      #pragma unroll
      for (int g = 0; g < 16; ++g) sacc += red[g][node];
      h0[(size_t)(base + node) * 8 + h] = sacc + bs2[h];
    }
    __syncthreads();
  }
}

// fused SA layer: per (node,head) thread, CSR edge loop, online softmax, residual+elu,
// optional head-mean (layer 0)
__global__ __launch_bounds__(256) void k_sa(const float* __restrict__ h_in,
                                            float* __restrict__ h_out,
                                            const int* __restrict__ rowPtr,
                                            const int* __restrict__ csrSrc,
                                            const int* __restrict__ csrType,
                                            const float* __restrict__ sa_w,
                                            const float* __restrict__ sa_al,
                                            const float* __restrict__ sa_ar,
                                            const float* __restrict__ saTab, int layer) {
  int t = blockIdx.x * 256 + threadIdx.x;
  int node = t >> 3, h = t & 7;
  float wgt = sa_w[layer * 8 + h];
  float al = sa_al[layer * 8 + h];
  float ar = sa_ar[layer * 8 + h];
  const float* tab = saTab + layer * 128;
  float zd = h_in[node * 8 + h] * wgt;
  int s0 = rowPtr[node], s1 = rowPtr[node + 1];
  float m = -INFINITY, lsum = 0.f, acc = 0.f;
  for (int i = s0; i < s1; ++i) {
    int s = csrSrc[i], ty = csrType[i];
    float zs = h_in[s * 8 + h] * wgt;
    float e = zs * al + zd * ar + tab[ty * 8 + h];
    e = (e >= 0.f) ? e : 0.2f * e;
    float nm = fmaxf(m, e);
    float scl = expf(m - nm);
    float p = expf(e - nm);
    acc = acc * scl + p * zs;
    lsum = lsum * scl + p;
    m = nm;
  }
  float o = acc / (lsum + 1e-9f);
  float r = o + zd;
  r = (r > 0.f) ? r : expm1f(r);
  if (layer == 0) {
    r += __shfl_xor(r, 1);
    r += __shfl_xor(r, 2);
    r += __shfl_xor(r, 4);
    r *= 0.125f;
  }
  h_out[node * 8 + h] = r;
}

// ---------------- semantic channel ----------------

// q,k,v = X @ {Wq,Wk,Wv} + bias.  block = 16 nodes, thread -> (node=t&15, colgroup=t>>4 of 16 cols)
__global__ __launch_bounds__(256) void k_qkv(const float* __restrict__ X,
                                             const float* __restrict__ Wq, const float* __restrict__ bq,
                                             const float* __restrict__ Wk, const float* __restrict__ bk,
                                             const float* __restrict__ Wv, const float* __restrict__ bv,
                                             float* __restrict__ q, float* __restrict__ k,
                                             float* __restrict__ v) {
  __shared__ float xs[16][260];
  int tid = threadIdx.x;
  int base = blockIdx.x * 16;
  const float4* X4 = (const float4*)(X + (size_t)base * 256);
  #pragma unroll
  for (int r = 0; r < 4; ++r) {
    int fi = tid + r * 256;
    int nd = fi >> 6, dq = fi & 63;
    *(float4*)&xs[nd][dq * 4] = X4[nd * 64 + dq];
  }
  __syncthreads();
  int node = tid & 15, cg = tid >> 4, c0 = cg * 16;
  const float* Ws[3] = {Wq, Wk, Wv};
  const float* bsv[3] = {bq, bk, bv};
  float* outs[3] = {q, k, v};
  #pragma unroll
  for (int mtx = 0; mtx < 3; ++mtx) {
    const float* W = Ws[mtx];
    float acc[16];
    #pragma unroll
    for (int j = 0; j < 16; ++j) acc[j] = 0.f;
    #pragma unroll 2
    for (int d = 0; d < 256; ++d) {
      float xv = xs[node][d];
      const float* wr = W + d * 256 + c0;
      float4 w0 = *(const float4*)(wr);
      float4 w1 = *(const float4*)(wr + 4);
      float4 w2 = *(const float4*)(wr + 8);
      float4 w3 = *(const float4*)(wr + 12);
      acc[0] += xv * w0.x; acc[1] += xv * w0.y; acc[2] += xv * w0.z; acc[3] += xv * w0.w;
      acc[4] += xv * w1.x; acc[5] += xv * w1.y; acc[6] += xv * w1.z; acc[7] += xv * w1.w;
      acc[8] += xv * w2.x; acc[9] += xv * w2.y; acc[10] += xv * w2.z; acc[11] += xv * w2.w;
      acc[12] += xv * w3.x; acc[13] += xv * w3.y; acc[14] += xv * w3.z; acc[15] += xv * w3.w;
    }
    float* op = outs[mtx] + (size_t)(base + node) * 256 + c0;
    const float* bp = bsv[mtx] + c0;
    #pragma unroll
    for (int j = 0; j < 16; j += 4) {
      float4 o;
      o.x = acc[j] + bp[j];
      o.y = acc[j + 1] + bp[j + 1];
      o.z = acc[j + 2] + bp[j + 2];
      o.w = acc[j + 3] + bp[j + 3];
      *(float4*)(op + j) = o;
    }
  }
}

// fused GT edge phase: wave per node; lane owns 4 cols (head = lane/8); flash softmax over
// CSR edges; score = sum_dh q[dst]*k[src]*epTab[type] / sqrt(DH); PV + residual.
__global__ __launch_bounds__(256) void k_gt(const float* __restrict__ q,
                                            const float* __restrict__ k,
                                            const float* __restrict__ v,
                                            const float* __restrict__ epTab,
                                            const float* __restrict__ feats_sem,
                                            const int* __restrict__ rowPtr,
                                            const int* __restrict__ csrSrc,
                                            const int* __restrict__ csrType,
                                            float* __restrict__ agg) {
  int node = blockIdx.x * 4 + (threadIdx.x >> 6);
  int lane = threadIdx.x & 63;
  int c0 = lane * 4;
  const float SC = 0.17677669529663687f;  // 1/sqrt(32)
  float4 qv = *(const float4*)(q + (size_t)node * 256 + c0);
  qv.x *= SC; qv.y *= SC; qv.z *= SC; qv.w *= SC;
  float4 acc = {0.f, 0.f, 0.f, 0.f};
  float m = -INFINITY, lsum = 0.f;
  int s0 = rowPtr[node], s1 = rowPtr[node + 1];
  for (int i = s0; i < s1; ++i) {
    int s = csrSrc[i], ty = csrType[i];
    float4 kv = *(const float4*)(k + (size_t)s * 256 + c0);
    float4 ep = *(const float4*)(epTab + ty * 256 + c0);
    float part = qv.x * kv.x * ep.x + qv.y * kv.y * ep.y +
                 qv.z * kv.z * ep.z + qv.w * kv.w * ep.w;
    part += __shfl_xor(part, 1);
    part += __shfl_xor(part, 2);
    part += __shfl_xor(part, 4);   // 8-lane head-group reduce -> full head score
    float nm = fmaxf(m, part);
    float scl = expf(m - nm);
    float p = expf(part - nm);
    float4 vv = *(const float4*)(v + (size_t)s * 256 + c0);
    acc.x = acc.x * scl + p * vv.x;
    acc.y = acc.y * scl + p * vv.y;
    acc.z = acc.z * scl + p * vv.z;
    acc.w = acc.w * scl + p * vv.w;
    lsum = lsum * scl + p;
    m = nm;
  }
  float inv = 1.f / (lsum + 1e-9f);
  float4 fs = *(const float4*)(feats_sem + (size_t)node * 256 + c0);
  float4 r;
  r.x = acc.x * inv + fs.x;
  r.y = acc.y * inv + fs.y;
  r.z = acc.z * inv + fs.z;
  r.w = acc.w * inv + fs.w;
  *(float4*)(agg + (size_t)node * 256 + c0) = r;
}

__global__ void k_bnstats(const float* __restrict__ agg, double* __restrict__ colsum,
                          double* __restrict__ colssq) {
  int t = threadIdx.x;
  int r0 = blockIdx.x * 79;
  int r1 = min(r0 + 79, N_NODES);
  double s = 0.0, qq = 0.0;
  for (int r = r0; r < r1; ++r) {
    float x = agg[(size_t)r * 256 + t];
    s += (double)x;
    qq += (double)x * (double)x;
  }
  atomicAdd(&colsum[t], s);
  atomicAdd(&colssq[t], qq);
}

__global__ void k_bnfinal(const double* __restrict__ colsum, const double* __restrict__ colssq,
                          float* __restrict__ muArr, float* __restrict__ invArr) {
  int t = threadIdx.x;
  double mu = colsum[t] / (double)N_NODES;
  double var = colssq[t] / (double)N_NODES - mu * mu;
  muArr[t] = (float)mu;
  invArr[t] = (float)(1.0 / sqrt(var + 1e-5));
}

// batchnorm apply + relu + Wout dot + fusion + centrality scaling + head mean + leaky_relu
__global__ __launch_bounds__(256) void k_final(const float* __restrict__ agg,
                                               const float* __restrict__ muArr,
                                               const float* __restrict__ invArr,
                                               const float* __restrict__ bn_gamma,
                                               const float* __restrict__ bn_beta,
                                               const float* __restrict__ Wout,
                                               const float* __restrict__ bout,
                                               const float* __restrict__ hB,
                                               const float* __restrict__ cent,
                                               const float* __restrict__ gamma,
                                               const float* __restrict__ beta,
                                               float* __restrict__ out) {
  int node = blockIdx.x * 4 + (threadIdx.x >> 6);
  int lane = threadIdx.x & 63;
  int c0 = lane * 4;
  float4 x = *(const float4*)(agg + (size_t)node * 256 + c0);
  float4 mu = *(const float4*)(muArr + c0);
  float4 iv = *(const float4*)(invArr + c0);
  float4 g = *(const float4*)(bn_gamma + c0);
  float4 b = *(const float4*)(bn_beta + c0);
  float4 w = *(const float4*)(Wout + c0);
  float p = fmaxf((x.x - mu.x) * iv.x * g.x + b.x, 0.f) * w.x +
            fmaxf((x.y - mu.y) * iv.y * g.y + b.y, 0.f) * w.y +
            fmaxf((x.z - mu.z) * iv.z * g.z + b.z, 0.f) * w.z +
            fmaxf((x.w - mu.w) * iv.w * g.w + b.w, 0.f) * w.w;
  #pragma unroll
  for (int o = 1; o < 64; o <<= 1) p += __shfl_xor(p, o);
  float ls = p + bout[0];
  int h = lane & 7;
  float logit = 0.5f * hB[(size_t)node * 8 + h] + 0.5f * ls;
  float sc = (cent[node] * gamma[h] + beta[h]) * logit;
  sc += __shfl_xor(sc, 1);
  sc += __shfl_xor(sc, 2);
  sc += __shfl_xor(sc, 4);
  float mn = sc * 0.125f;
  mn = (mn >= 0.f) ? mn : 0.01f * mn;
  if (lane == 0) out[node] = mn;
}

// ---------------- launch ----------------

extern "C" void kernel_launch(void* const* d_in, const int* in_sizes, int n_in,
                              void* d_out, int out_size, void* d_ws, size_t ws_size,
                              hipStream_t stream) {
  (void)in_sizes; (void)n_in; (void)out_size; (void)ws_size;
  const float* feats_struct = (const float*)d_in[0];
  const float* feats_sem    = (const float*)d_in[1];
  const float* cent         = (const float*)d_in[2];
  const float* Ws1          = (const float*)d_in[3];
  const float* bs1          = (const float*)d_in[4];
  const float* Ws2          = (const float*)d_in[5];
  const float* bs2          = (const float*)d_in[6];
  const float* rel_emb      = (const float*)d_in[7];
  const float* sa_w         = (const float*)d_in[8];
  const float* sa_al        = (const float*)d_in[9];
  const float* sa_ar        = (const float*)d_in[10];
  const float* sa_We        = (const float*)d_in[11];
  const float* Wq           = (const float*)d_in[12];
  const float* bq           = (const float*)d_in[13];
  const float* Wk           = (const float*)d_in[14];
  const float* bk           = (const float*)d_in[15];
  const float* Wv           = (const float*)d_in[16];
  const float* bv           = (const float*)d_in[17];
  const float* We_gt        = (const float*)d_in[18];
  const float* bn_gamma     = (const float*)d_in[19];
  const float* bn_beta      = (const float*)d_in[20];
  const float* Wout         = (const float*)d_in[21];
  const float* bout         = (const float*)d_in[22];
  const float* gamma        = (const float*)d_in[23];
  const float* beta         = (const float*)d_in[24];
  const int* e_type         = (const int*)d_in[25];
  const int* e_src          = (const int*)d_in[26];
  const int* e_dst          = (const int*)d_in[27];
  float* out = (float*)d_out;

  char* wsb = (char*)d_ws;
  size_t off = 0;
  auto alloc = [&](size_t bytes) -> char* {
    char* p = wsb + off;
    off = (off + bytes + 255) & ~(size_t)255;
    return p;
  };
  float* saTab   = (float*)alloc(2 * 16 * 8 * 4);
  float* epTab   = (float*)alloc(16 * 256 * 4);
  int* deg       = (int*)alloc((size_t)N_NODES * 4);
  int* rowPtr    = (int*)alloc((size_t)(N_NODES + 1) * 4);
  int* cursor    = (int*)alloc((size_t)N_NODES * 4);
  int* csrSrc    = (int*)alloc((size_t)N_EDGES * 4);
  int* csrType   = (int*)alloc((size_t)N_EDGES * 4);
  float* h0      = (float*)alloc((size_t)N_NODES * 8 * 4);
  float* hA      = (float*)alloc((size_t)N_NODES * 8 * 4);
  float* hB      = (float*)alloc((size_t)N_NODES * 8 * 4);
  float* qb      = (float*)alloc((size_t)N_NODES * 256 * 4);
  float* kb      = (float*)alloc((size_t)N_NODES * 256 * 4);
  float* vb      = (float*)alloc((size_t)N_NODES * 256 * 4);
  float* agg     = (float*)alloc((size_t)N_NODES * 256 * 4);
  double* colsum = (double*)alloc(256 * 8);
  double* colssq = (double*)alloc(256 * 8);
  float* muArr   = (float*)alloc(256 * 4);
  float* invArr  = (float*)alloc(256 * 4);

  hipMemsetAsync(deg, 0, (size_t)N_NODES * 4, stream);
  hipMemsetAsync(colsum, 0, 256 * 8, stream);
  hipMemsetAsync(colssq, 0, 256 * 8, stream);

  k_tables<<<1, 256, 0, stream>>>(rel_emb, sa_We, We_gt, saTab, epTab);
  k_hist<<<(N_EDGES + 255) / 256, 256, 0, stream>>>(e_dst, deg);
  k_scan<<<1, 256, 0, stream>>>(deg, rowPtr, cursor);
  k_fill<<<(N_EDGES + 255) / 256, 256, 0, stream>>>(e_dst, e_src, e_type, cursor, csrSrc, csrType);

  k_mlp<<<N_NODES / 16, 256, 0, stream>>>(feats_struct, Ws1, bs1, Ws2, bs2, h0);
  k_sa<<<N_NODES * 8 / 256, 256, 0, stream>>>(h0, hA, rowPtr, csrSrc, csrType,
                                              sa_w, sa_al, sa_ar, saTab, 0);
  k_sa<<<N_NODES * 8 / 256, 256, 0, stream>>>(hA, hB, rowPtr, csrSrc, csrType,
                                              sa_w, sa_al, sa_ar, saTab, 1);

  k_qkv<<<N_NODES / 16, 256, 0, stream>>>(feats_sem, Wq, bq, Wk, bk, Wv, bv, qb, kb, vb);
  k_gt<<<N_NODES / 4, 256, 0, stream>>>(qb, kb, vb, epTab, feats_sem,
                                        rowPtr, csrSrc, csrType, agg);
  k_bnstats<<<256, 256, 0, stream>>>(agg, colsum, colssq);
  k_bnfinal<<<1, 256, 0, stream>>>(colsum, colssq, muArr, invArr);
  k_final<<<N_NODES / 4, 256, 0, stream>>>(agg, muArr, invArr, bn_gamma, bn_beta,
                                           Wout, bout, hB, cent, gamma, beta, out);
}

// Round 3
// 440.606 us; speedup vs baseline: 3.0802x; 3.0802x over previous
//
#include <hip/hip_runtime.h>
#include <hip/hip_bf16.h>
#include <math.h>

#define N_NODES 20000
#define N_EDGES 256000

typedef __attribute__((ext_vector_type(8))) __bf16 bf16x8;
typedef __attribute__((ext_vector_type(8))) unsigned short u16x8;
typedef __attribute__((ext_vector_type(4))) float f32x4;

static __device__ __forceinline__ unsigned short f2bf(float f) {
  unsigned u = __float_as_uint(f);
  unsigned r = (u + 0x7fffu + ((u >> 16) & 1u)) >> 16;
  return (unsigned short)r;
}

// ---------------- small setup kernels ----------------

// saTab[l][r][h] = sum_p rel_emb[r,p] * sa_We[l,p,h]   (2*16*8 = 256)
// epTab[r][c]    = sum_p rel_emb[r,p] * We_gt[p,c]     (16*256)
__global__ void k_tables(const float* __restrict__ rel_emb,
                         const float* __restrict__ sa_We,
                         const float* __restrict__ We_gt,
                         float* __restrict__ saTab, float* __restrict__ epTab) {
  int t = threadIdx.x;
  {
    int l = t >> 7, r = (t >> 3) & 15, h = t & 7;
    float acc = 0.f;
    for (int p = 0; p < 32; ++p)
      acc += rel_emb[r * 32 + p] * sa_We[l * 256 + p * 8 + h];
    saTab[t] = acc;
  }
  for (int r = 0; r < 16; ++r) {
    float acc = 0.f;
    for (int p = 0; p < 32; ++p)
      acc += rel_emb[r * 32 + p] * We_gt[p * 256 + t];
    epTab[r * 256 + t] = acc;
  }
}

__global__ void k_hist(const int* __restrict__ e_dst, int* __restrict__ deg) {
  int e = blockIdx.x * 256 + threadIdx.x;
  if (e < N_EDGES) atomicAdd(&deg[e_dst[e]], 1);
}

__global__ void k_scan(const int* __restrict__ deg, int* __restrict__ rowPtr,
                       int* __restrict__ cursor) {
  const int CH = (N_NODES + 255) / 256;  // 79
  int t = threadIdx.x;
  int b0 = t * CH, b1 = min(b0 + CH, N_NODES);
  int s = 0;
  for (int i = b0; i < b1; ++i) s += deg[i];
  __shared__ int part[256];
  part[t] = s;
  __syncthreads();
  for (int off = 1; off < 256; off <<= 1) {
    int add = (t >= off) ? part[t - off] : 0;
    __syncthreads();
    part[t] += add;
    __syncthreads();
  }
  int run = (t == 0) ? 0 : part[t - 1];
  for (int i = b0; i < b1; ++i) {
    rowPtr[i] = run;
    cursor[i] = run;
    run += deg[i];
  }
  if (t == 0) rowPtr[N_NODES] = part[255];
}

__global__ void k_fill(const int* __restrict__ e_dst, const int* __restrict__ e_src,
                       const int* __restrict__ e_type, int* __restrict__ cursor,
                       int* __restrict__ csrSrc, int* __restrict__ csrType) {
  int e = blockIdx.x * 256 + threadIdx.x;
  if (e >= N_EDGES) return;
  int d = e_dst[e];
  int pos = atomicAdd(&cursor[d], 1);
  csrSrc[pos] = e_src[e];
  csrType[pos] = e_type[e];
}

// ---------------- bf16 conversion / weight transposes ----------------

__global__ void k_convX(const float* __restrict__ Xs, const float* __restrict__ Xm,
                        ushort* __restrict__ Xsb, ushort* __restrict__ Xmb) {
  size_t i = ((size_t)blockIdx.x * 256 + threadIdx.x) * 4;
  float4 a = *(const float4*)(Xs + i);
  ushort4 ua = {f2bf(a.x), f2bf(a.y), f2bf(a.z), f2bf(a.w)};
  *(ushort4*)(Xsb + i) = ua;
  float4 b = *(const float4*)(Xm + i);
  ushort4 ub = {f2bf(b.x), f2bf(b.y), f2bf(b.z), f2bf(b.w)};
  *(ushort4*)(Xmb + i) = ub;
}

// Ws1t[h][k][d] = bf16(Ws1[h][d][k])   (B^T layout)
__global__ void k_tws1(const float* __restrict__ Ws1, ushort* __restrict__ Ws1t) {
  int h = blockIdx.x >> 7, kcol = blockIdx.x & 127, d = threadIdx.x;
  Ws1t[((size_t)h * 128 + kcol) * 256 + d] = f2bf(Ws1[((size_t)h * 256 + d) * 128 + kcol]);
}

// Wt[m][n][d] = bf16(W_m[d][n])
__global__ void k_twqkv(const float* __restrict__ Wq, const float* __restrict__ Wk,
                        const float* __restrict__ Wv, ushort* __restrict__ Wt) {
  int m = blockIdx.x >> 8, n = blockIdx.x & 255, d = threadIdx.x;
  const float* W = (m == 0) ? Wq : (m == 1) ? Wk : Wv;
  Wt[((size_t)m * 256 + n) * 256 + d] = f2bf(W[(size_t)d * 256 + n]);
}

// ---------------- structural channel (MFMA) ----------------

// block: 64 nodes (4 waves x 16), head = blockIdx.y.
// C = X[64x256] @ Ws1[h]^T-tile, epilogue relu()*Ws2 reduce -> h0[node][h]
__global__ __launch_bounds__(256) void k_mlp_mfma(
    const ushort* __restrict__ Xb, const ushort* __restrict__ Ws1t,
    const float* __restrict__ bs1, const float* __restrict__ Ws2,
    const float* __restrict__ bs2, float* __restrict__ h0) {
  __shared__ ushort Ab[64][136];   // 64 nodes x 128 K-chunk (pad 8 -> 272B stride)
  __shared__ ushort Bb[128][136];  // 128 cols x 128 K-chunk
  int tid = threadIdx.x;
  int h = blockIdx.y;
  int base = blockIdx.x * 64;
  int wv = tid >> 6, lane = tid & 63;
  int l15 = lane & 15, lhi = lane >> 4;
  f32x4 acc[8];
  #pragma unroll
  for (int nt = 0; nt < 8; ++nt) acc[nt] = (f32x4){0.f, 0.f, 0.f, 0.f};

  for (int kc = 0; kc < 2; ++kc) {
    {  // stage A (16KB): row = tid>>2, 4 x 16B segs
      int r = tid >> 2, c4 = (tid & 3) * 4;
      int gr = base + r;
      const ushort* src = Xb + (size_t)gr * 256 + kc * 128;
      #pragma unroll
      for (int s = 0; s < 4; ++s) {
        u16x8 val = {0, 0, 0, 0, 0, 0, 0, 0};
        if (gr < N_NODES) val = *(const u16x8*)(src + (c4 + s) * 8);
        *(u16x8*)&Ab[r][(c4 + s) * 8] = val;
      }
    }
    {  // stage B (32KB): row = tid>>1, 8 x 16B segs
      int r = tid >> 1, cb = (tid & 1) * 8;
      const ushort* src = Ws1t + ((size_t)h * 128 + r) * 256 + kc * 128;
      #pragma unroll
      for (int s = 0; s < 8; ++s)
        *(u16x8*)&Bb[r][(cb + s) * 8] = *(const u16x8*)(src + (cb + s) * 8);
    }
    __syncthreads();
    #pragma unroll
    for (int kk = 0; kk < 4; ++kk) {
      bf16x8 a = *(const bf16x8*)&Ab[wv * 16 + l15][kk * 32 + lhi * 8];
      #pragma unroll
      for (int nt = 0; nt < 8; ++nt) {
        bf16x8 b = *(const bf16x8*)&Bb[nt * 16 + l15][kk * 32 + lhi * 8];
        acc[nt] = __builtin_amdgcn_mfma_f32_16x16x32_bf16(a, b, acc[nt], 0, 0, 0);
      }
    }
    __syncthreads();
  }
  // epilogue: h = sum_c relu(h1 + bs1[c]) * Ws2[c];  c = nt*16 + l15, rows = lhi*4+j
  float part[4] = {0.f, 0.f, 0.f, 0.f};
  #pragma unroll
  for (int nt = 0; nt < 8; ++nt) {
    int c = h * 128 + nt * 16 + l15;
    float b1 = bs1[c], w2 = Ws2[c];
    #pragma unroll
    for (int j = 0; j < 4; ++j)
      part[j] += fmaxf(acc[nt][j] + b1, 0.f) * w2;
  }
  #pragma unroll
  for (int j = 0; j < 4; ++j) {
    #pragma unroll
    for (int o = 1; o < 16; o <<= 1) part[j] += __shfl_xor(part[j], o);
  }
  if (l15 == 0) {
    float b2 = bs2[h];
    #pragma unroll
    for (int j = 0; j < 4; ++j) {
      int row = base + wv * 16 + lhi * 4 + j;
      if (row < N_NODES) h0[(size_t)row * 8 + h] = part[j] + b2;
    }
  }
}

// ---------------- semantic channel QKV (MFMA) ----------------

// blockIdx.y: m = y>>1 in {q,k,v}, half = y&1 (128-col half). 64 nodes per block.
__global__ __launch_bounds__(256) void k_qkv_mfma(
    const ushort* __restrict__ Xb, const ushort* __restrict__ Wt,
    const float* __restrict__ bq, const float* __restrict__ bk,
    const float* __restrict__ bv, float* __restrict__ q,
    float* __restrict__ k, float* __restrict__ v) {
  __shared__ ushort Ab[64][136];
  __shared__ ushort Bb[128][136];
  int tid = threadIdx.x;
  int m = blockIdx.y >> 1, half = blockIdx.y & 1;
  int base = blockIdx.x * 64;
  int wv = tid >> 6, lane = tid & 63;
  int l15 = lane & 15, lhi = lane >> 4;
  f32x4 acc[8];
  #pragma unroll
  for (int nt = 0; nt < 8; ++nt) acc[nt] = (f32x4){0.f, 0.f, 0.f, 0.f};

  for (int kc = 0; kc < 2; ++kc) {
    {
      int r = tid >> 2, c4 = (tid & 3) * 4;
      int gr = base + r;
      const ushort* src = Xb + (size_t)gr * 256 + kc * 128;
      #pragma unroll
      for (int s = 0; s < 4; ++s) {
        u16x8 val = {0, 0, 0, 0, 0, 0, 0, 0};
        if (gr < N_NODES) val = *(const u16x8*)(src + (c4 + s) * 8);
        *(u16x8*)&Ab[r][(c4 + s) * 8] = val;
      }
    }
    {
      int r = tid >> 1, cb = (tid & 1) * 8;
      const ushort* src = Wt + (((size_t)m * 256 + half * 128 + r) * 256) + kc * 128;
      #pragma unroll
      for (int s = 0; s < 8; ++s)
        *(u16x8*)&Bb[r][(cb + s) * 8] = *(const u16x8*)(src + (cb + s) * 8);
    }
    __syncthreads();
    #pragma unroll
    for (int kk = 0; kk < 4; ++kk) {
      bf16x8 a = *(const bf16x8*)&Ab[wv * 16 + l15][kk * 32 + lhi * 8];
      #pragma unroll
      for (int nt = 0; nt < 8; ++nt) {
        bf16x8 b = *(const bf16x8*)&Bb[nt * 16 + l15][kk * 32 + lhi * 8];
        acc[nt] = __builtin_amdgcn_mfma_f32_16x16x32_bf16(a, b, acc[nt], 0, 0, 0);
      }
    }
    __syncthreads();
  }
  float* out = (m == 0) ? q : (m == 1) ? k : v;
  const float* bias = (m == 0) ? bq : (m == 1) ? bk : bv;
  #pragma unroll
  for (int nt = 0; nt < 8; ++nt) {
    int c = half * 128 + nt * 16 + l15;
    float bc = bias[c];
    #pragma unroll
    for (int j = 0; j < 4; ++j) {
      int row = base + wv * 16 + lhi * 4 + j;
      if (row < N_NODES) out[(size_t)row * 256 + c] = acc[nt][j] + bc;
    }
  }
}

// ---------------- SA layers ----------------

__global__ __launch_bounds__(256) void k_sa(const float* __restrict__ h_in,
                                            float* __restrict__ h_out,
                                            const int* __restrict__ rowPtr,
                                            const int* __restrict__ csrSrc,
                                            const int* __restrict__ csrType,
                                            const float* __restrict__ sa_w,
                                            const float* __restrict__ sa_al,
                                            const float* __restrict__ sa_ar,
                                            const float* __restrict__ saTab, int layer) {
  int t = blockIdx.x * 256 + threadIdx.x;
  int node = t >> 3, h = t & 7;
  float wgt = sa_w[layer * 8 + h];
  float al = sa_al[layer * 8 + h];
  float ar = sa_ar[layer * 8 + h];
  const float* tab = saTab + layer * 128;
  float zd = h_in[node * 8 + h] * wgt;
  int s0 = rowPtr[node], s1 = rowPtr[node + 1];
  float m = -INFINITY, lsum = 0.f, acc = 0.f;
  for (int i = s0; i < s1; ++i) {
    int s = csrSrc[i], ty = csrType[i];
    float zs = h_in[s * 8 + h] * wgt;
    float e = zs * al + zd * ar + tab[ty * 8 + h];
    e = (e >= 0.f) ? e : 0.2f * e;
    float nm = fmaxf(m, e);
    float scl = expf(m - nm);
    float p = expf(e - nm);
    acc = acc * scl + p * zs;
    lsum = lsum * scl + p;
    m = nm;
  }
  float o = acc / (lsum + 1e-9f);
  float r = o + zd;
  r = (r > 0.f) ? r : expm1f(r);
  if (layer == 0) {
    r += __shfl_xor(r, 1);
    r += __shfl_xor(r, 2);
    r += __shfl_xor(r, 4);
    r *= 0.125f;
  }
  h_out[node * 8 + h] = r;
}

// ---------------- GT edge phase ----------------

__global__ __launch_bounds__(256) void k_gt(const float* __restrict__ q,
                                            const float* __restrict__ k,
                                            const float* __restrict__ v,
                                            const float* __restrict__ epTab,
                                            const float* __restrict__ feats_sem,
                                            const int* __restrict__ rowPtr,
                                            const int* __restrict__ csrSrc,
                                            const int* __restrict__ csrType,
                                            float* __restrict__ agg) {
  int node = blockIdx.x * 4 + (threadIdx.x >> 6);
  int lane = threadIdx.x & 63;
  int c0 = lane * 4;
  const float SC = 0.17677669529663687f;  // 1/sqrt(32)
  float4 qv = *(const float4*)(q + (size_t)node * 256 + c0);
  qv.x *= SC; qv.y *= SC; qv.z *= SC; qv.w *= SC;
  float4 acc = {0.f, 0.f, 0.f, 0.f};
  float m = -INFINITY, lsum = 0.f;
  int s0 = rowPtr[node], s1 = rowPtr[node + 1];
  for (int i = s0; i < s1; ++i) {
    int s = csrSrc[i], ty = csrType[i];
    float4 kv = *(const float4*)(k + (size_t)s * 256 + c0);
    float4 ep = *(const float4*)(epTab + ty * 256 + c0);
    float part = qv.x * kv.x * ep.x + qv.y * kv.y * ep.y +
                 qv.z * kv.z * ep.z + qv.w * kv.w * ep.w;
    part += __shfl_xor(part, 1);
    part += __shfl_xor(part, 2);
    part += __shfl_xor(part, 4);
    float nm = fmaxf(m, part);
    float scl = expf(m - nm);
    float p = expf(part - nm);
    float4 vv = *(const float4*)(v + (size_t)s * 256 + c0);
    acc.x = acc.x * scl + p * vv.x;
    acc.y = acc.y * scl + p * vv.y;
    acc.z = acc.z * scl + p * vv.z;
    acc.w = acc.w * scl + p * vv.w;
    lsum = lsum * scl + p;
    m = nm;
  }
  float inv = 1.f / (lsum + 1e-9f);
  float4 fs = *(const float4*)(feats_sem + (size_t)node * 256 + c0);
  float4 r;
  r.x = acc.x * inv + fs.x;
  r.y = acc.y * inv + fs.y;
  r.z = acc.z * inv + fs.z;
  r.w = acc.w * inv + fs.w;
  *(float4*)(agg + (size_t)node * 256 + c0) = r;
}

__global__ void k_bnstats(const float* __restrict__ agg, double* __restrict__ colsum,
                          double* __restrict__ colssq) {
  int t = threadIdx.x;
  int r0 = blockIdx.x * 79;
  int r1 = min(r0 + 79, N_NODES);
  double s = 0.0, qq = 0.0;
  for (int r = r0; r < r1; ++r) {
    float x = agg[(size_t)r * 256 + t];
    s += (double)x;
    qq += (double)x * (double)x;
  }
  atomicAdd(&colsum[t], s);
  atomicAdd(&colssq[t], qq);
}

__global__ void k_bnfinal(const double* __restrict__ colsum, const double* __restrict__ colssq,
                          float* __restrict__ muArr, float* __restrict__ invArr) {
  int t = threadIdx.x;
  double mu = colsum[t] / (double)N_NODES;
  double var = colssq[t] / (double)N_NODES - mu * mu;
  muArr[t] = (float)mu;
  invArr[t] = (float)(1.0 / sqrt(var + 1e-5));
}

__global__ __launch_bounds__(256) void k_final(const float* __restrict__ agg,
                                               const float* __restrict__ muArr,
                                               const float* __restrict__ invArr,
                                               const float* __restrict__ bn_gamma,
                                               const float* __restrict__ bn_beta,
                                               const float* __restrict__ Wout,
                                               const float* __restrict__ bout,
                                               const float* __restrict__ hB,
                                               const float* __restrict__ cent,
                                               const float* __restrict__ gamma,
                                               const float* __restrict__ beta,
                                               float* __restrict__ out) {
  int node = blockIdx.x * 4 + (threadIdx.x >> 6);
  int lane = threadIdx.x & 63;
  int c0 = lane * 4;
  float4 x = *(const float4*)(agg + (size_t)node * 256 + c0);
  float4 mu = *(const float4*)(muArr + c0);
  float4 iv = *(const float4*)(invArr + c0);
  float4 g = *(const float4*)(bn_gamma + c0);
  float4 b = *(const float4*)(bn_beta + c0);
  float4 w = *(const float4*)(Wout + c0);
  float p = fmaxf((x.x - mu.x) * iv.x * g.x + b.x, 0.f) * w.x +
            fmaxf((x.y - mu.y) * iv.y * g.y + b.y, 0.f) * w.y +
            fmaxf((x.z - mu.z) * iv.z * g.z + b.z, 0.f) * w.z +
            fmaxf((x.w - mu.w) * iv.w * g.w + b.w, 0.f) * w.w;
  #pragma unroll
  for (int o = 1; o < 64; o <<= 1) p += __shfl_xor(p, o);
  float ls = p + bout[0];
  int h = lane & 7;
  float logit = 0.5f * hB[(size_t)node * 8 + h] + 0.5f * ls;
  float sc = (cent[node] * gamma[h] + beta[h]) * logit;
  sc += __shfl_xor(sc, 1);
  sc += __shfl_xor(sc, 2);
  sc += __shfl_xor(sc, 4);
  float mn = sc * 0.125f;
  mn = (mn >= 0.f) ? mn : 0.01f * mn;
  if (lane == 0) out[node] = mn;
}

// ---------------- launch ----------------

extern "C" void kernel_launch(void* const* d_in, const int* in_sizes, int n_in,
                              void* d_out, int out_size, void* d_ws, size_t ws_size,
                              hipStream_t stream) {
  (void)in_sizes; (void)n_in; (void)out_size; (void)ws_size;
  const float* feats_struct = (const float*)d_in[0];
  const float* feats_sem    = (const float*)d_in[1];
  const float* cent         = (const float*)d_in[2];
  const float* Ws1          = (const float*)d_in[3];
  const float* bs1          = (const float*)d_in[4];
  const float* Ws2          = (const float*)d_in[5];
  const float* bs2          = (const float*)d_in[6];
  const float* rel_emb      = (const float*)d_in[7];
  const float* sa_w         = (const float*)d_in[8];
  const float* sa_al        = (const float*)d_in[9];
  const float* sa_ar        = (const float*)d_in[10];
  const float* sa_We        = (const float*)d_in[11];
  const float* Wq           = (const float*)d_in[12];
  const float* bq           = (const float*)d_in[13];
  const float* Wk           = (const float*)d_in[14];
  const float* bk           = (const float*)d_in[15];
  const float* Wv           = (const float*)d_in[16];
  const float* bv           = (const float*)d_in[17];
  const float* We_gt        = (const float*)d_in[18];
  const float* bn_gamma     = (const float*)d_in[19];
  const float* bn_beta      = (const float*)d_in[20];
  const float* Wout         = (const float*)d_in[21];
  const float* bout         = (const float*)d_in[22];
  const float* gamma        = (const float*)d_in[23];
  const float* beta         = (const float*)d_in[24];
  const int* e_type         = (const int*)d_in[25];
  const int* e_src          = (const int*)d_in[26];
  const int* e_dst          = (const int*)d_in[27];
  float* out = (float*)d_out;

  char* wsb = (char*)d_ws;
  size_t off = 0;
  auto alloc = [&](size_t bytes) -> char* {
    char* p = wsb + off;
    off = (off + bytes + 255) & ~(size_t)255;
    return p;
  };
  float* saTab   = (float*)alloc(2 * 16 * 8 * 4);
  float* epTab   = (float*)alloc(16 * 256 * 4);
  int* deg       = (int*)alloc((size_t)N_NODES * 4);
  int* rowPtr    = (int*)alloc((size_t)(N_NODES + 1) * 4);
  int* cursor    = (int*)alloc((size_t)N_NODES * 4);
  int* csrSrc    = (int*)alloc((size_t)N_EDGES * 4);
  int* csrType   = (int*)alloc((size_t)N_EDGES * 4);
  float* h0      = (float*)alloc((size_t)N_NODES * 8 * 4);
  float* hA      = (float*)alloc((size_t)N_NODES * 8 * 4);
  float* hB      = (float*)alloc((size_t)N_NODES * 8 * 4);
  float* qb      = (float*)alloc((size_t)N_NODES * 256 * 4);
  float* kb      = (float*)alloc((size_t)N_NODES * 256 * 4);
  float* vb      = (float*)alloc((size_t)N_NODES * 256 * 4);
  float* agg     = (float*)alloc((size_t)N_NODES * 256 * 4);
  double* colsum = (double*)alloc(256 * 8);
  double* colssq = (double*)alloc(256 * 8);
  float* muArr   = (float*)alloc(256 * 4);
  float* invArr  = (float*)alloc(256 * 4);
  ushort* Xsb    = (ushort*)alloc((size_t)N_NODES * 256 * 2);
  ushort* Xmb    = (ushort*)alloc((size_t)N_NODES * 256 * 2);
  ushort* Ws1t   = (ushort*)alloc((size_t)8 * 128 * 256 * 2);
  ushort* Wqkvt  = (ushort*)alloc((size_t)3 * 256 * 256 * 2);

  hipMemsetAsync(deg, 0, (size_t)N_NODES * 4, stream);
  hipMemsetAsync(colsum, 0, 256 * 8, stream);
  hipMemsetAsync(colssq, 0, 256 * 8, stream);

  k_tables<<<1, 256, 0, stream>>>(rel_emb, sa_We, We_gt, saTab, epTab);
  k_hist<<<(N_EDGES + 255) / 256, 256, 0, stream>>>(e_dst, deg);
  k_scan<<<1, 256, 0, stream>>>(deg, rowPtr, cursor);
  k_fill<<<(N_EDGES + 255) / 256, 256, 0, stream>>>(e_dst, e_src, e_type, cursor, csrSrc, csrType);

  k_convX<<<N_NODES * 256 / (256 * 4), 256, 0, stream>>>(feats_struct, feats_sem, Xsb, Xmb);
  k_tws1<<<8 * 128, 256, 0, stream>>>(Ws1, Ws1t);
  k_twqkv<<<3 * 256, 256, 0, stream>>>(Wq, Wk, Wv, Wqkvt);

  const int MT = (N_NODES + 63) / 64;  // 313
  dim3 gMlp(MT, 8);
  k_mlp_mfma<<<gMlp, 256, 0, stream>>>(Xsb, Ws1t, bs1, Ws2, bs2, h0);
  k_sa<<<N_NODES * 8 / 256, 256, 0, stream>>>(h0, hA, rowPtr, csrSrc, csrType,
                                              sa_w, sa_al, sa_ar, saTab, 0);
  k_sa<<<N_NODES * 8 / 256, 256, 0, stream>>>(hA, hB, rowPtr, csrSrc, csrType,
                                              sa_w, sa_al, sa_ar, saTab, 1);

  dim3 gQkv(MT, 6);
  k_qkv_mfma<<<gQkv, 256, 0, stream>>>(Xmb, Wqkvt, bq, bk, bv, qb, kb, vb);
  k_gt<<<N_NODES / 4, 256, 0, stream>>>(qb, kb, vb, epTab, feats_sem,
                                        rowPtr, csrSrc, csrType, agg);
  k_bnstats<<<256, 256, 0, stream>>>(agg, colsum, colssq);
  k_bnfinal<<<1, 256, 0, stream>>>(colsum, colssq, muArr, invArr);
  k_final<<<N_NODES / 4, 256, 0, stream>>>(agg, muArr, invArr, bn_gamma, bn_beta,
                                           Wout, bout, hB, cent, gamma, beta, out);
}

// Round 5
// 401.962 us; speedup vs baseline: 3.3763x; 1.0961x over previous
//
#include <hip/hip_runtime.h>
#include <hip/hip_bf16.h>
#include <math.h>

#define N_NODES 20000
#define N_EDGES 256000

typedef __attribute__((ext_vector_type(8))) __bf16 bf16x8;
typedef __attribute__((ext_vector_type(8))) unsigned short u16x8;
typedef __attribute__((ext_vector_type(4))) float f32x4;

static __device__ __forceinline__ unsigned short f2bf(float f) {
  unsigned u = __float_as_uint(f);
  unsigned r = (u + 0x7fffu + ((u >> 16) & 1u)) >> 16;
  return (unsigned short)r;
}
static __device__ __forceinline__ float b2f(unsigned short u) {
  return __uint_as_float((unsigned)u << 16);
}

// ---------------- small setup kernels ----------------

__global__ void k_tables(const float* __restrict__ rel_emb,
                         const float* __restrict__ sa_We,
                         const float* __restrict__ We_gt,
                         float* __restrict__ saTab, float* __restrict__ epTab) {
  int t = threadIdx.x;
  {
    int l = t >> 7, r = (t >> 3) & 15, h = t & 7;
    float acc = 0.f;
    for (int p = 0; p < 32; ++p)
      acc += rel_emb[r * 32 + p] * sa_We[l * 256 + p * 8 + h];
    saTab[t] = acc;
  }
  for (int r = 0; r < 16; ++r) {
    float acc = 0.f;
    for (int p = 0; p < 32; ++p)
      acc += rel_emb[r * 32 + p] * We_gt[p * 256 + t];
    epTab[r * 256 + t] = acc;
  }
}

__global__ void k_hist(const int* __restrict__ e_dst, int* __restrict__ deg) {
  int e = blockIdx.x * 256 + threadIdx.x;
  if (e < N_EDGES) atomicAdd(&deg[e_dst[e]], 1);
}

__global__ void k_scan(const int* __restrict__ deg, int* __restrict__ rowPtr,
                       int* __restrict__ cursor) {
  const int CH = (N_NODES + 255) / 256;  // 79
  int t = threadIdx.x;
  int b0 = t * CH, b1 = min(b0 + CH, N_NODES);
  int s = 0;
  for (int i = b0; i < b1; ++i) s += deg[i];
  __shared__ int part[256];
  part[t] = s;
  __syncthreads();
  for (int off = 1; off < 256; off <<= 1) {
    int add = (t >= off) ? part[t - off] : 0;
    __syncthreads();
    part[t] += add;
    __syncthreads();
  }
  int run = (t == 0) ? 0 : part[t - 1];
  for (int i = b0; i < b1; ++i) {
    rowPtr[i] = run;
    cursor[i] = run;
    run += deg[i];
  }
  if (t == 0) rowPtr[N_NODES] = part[255];
}

__global__ void k_fill(const int* __restrict__ e_dst, const int* __restrict__ e_src,
                       const int* __restrict__ e_type, int* __restrict__ cursor,
                       int* __restrict__ csrSrc, int* __restrict__ csrType) {
  int e = blockIdx.x * 256 + threadIdx.x;
  if (e >= N_EDGES) return;
  int d = e_dst[e];
  int pos = atomicAdd(&cursor[d], 1);
  csrSrc[pos] = e_src[e];
  csrType[pos] = e_type[e];
}

// ---------------- bf16 conversion / weight transposes ----------------

__global__ void k_convX(const float* __restrict__ Xs, const float* __restrict__ Xm,
                        ushort* __restrict__ Xsb, ushort* __restrict__ Xmb) {
  size_t i = ((size_t)blockIdx.x * 256 + threadIdx.x) * 4;
  float4 a = *(const float4*)(Xs + i);
  ushort4 ua = {f2bf(a.x), f2bf(a.y), f2bf(a.z), f2bf(a.w)};
  *(ushort4*)(Xsb + i) = ua;
  float4 b = *(const float4*)(Xm + i);
  ushort4 ub = {f2bf(b.x), f2bf(b.y), f2bf(b.z), f2bf(b.w)};
  *(ushort4*)(Xmb + i) = ub;
}

// Ws1t[h][k][d] = bf16(Ws1[h][d][k])   (B^T layout)
__global__ void k_tws1(const float* __restrict__ Ws1, ushort* __restrict__ Ws1t) {
  int h = blockIdx.x >> 7, kcol = blockIdx.x & 127, d = threadIdx.x;
  Ws1t[((size_t)h * 128 + kcol) * 256 + d] = f2bf(Ws1[((size_t)h * 256 + d) * 128 + kcol]);
}

// Wt[m][n][d] = bf16(W_m[d][n])
__global__ void k_twqkv(const float* __restrict__ Wq, const float* __restrict__ Wk,
                        const float* __restrict__ Wv, ushort* __restrict__ Wt) {
  int m = blockIdx.x >> 8, n = blockIdx.x & 255, d = threadIdx.x;
  const float* W = (m == 0) ? Wq : (m == 1) ? Wk : Wv;
  Wt[((size_t)m * 256 + n) * 256 + d] = f2bf(W[(size_t)d * 256 + n]);
}

// ---------------- structural channel (MFMA) ----------------

__global__ __launch_bounds__(256) void k_mlp_mfma(
    const ushort* __restrict__ Xb, const ushort* __restrict__ Ws1t,
    const float* __restrict__ bs1, const float* __restrict__ Ws2,
    const float* __restrict__ bs2, float* __restrict__ h0) {
  __shared__ ushort Ab[64][136];
  __shared__ ushort Bb[128][136];
  int tid = threadIdx.x;
  int h = blockIdx.y;
  int base = blockIdx.x * 64;
  int wv = tid >> 6, lane = tid & 63;
  int l15 = lane & 15, lhi = lane >> 4;
  f32x4 acc[8];
  #pragma unroll
  for (int nt = 0; nt < 8; ++nt) acc[nt] = (f32x4){0.f, 0.f, 0.f, 0.f};

  for (int kc = 0; kc < 2; ++kc) {
    {
      int r = tid >> 2, c4 = (tid & 3) * 4;
      int gr = base + r;
      const ushort* src = Xb + (size_t)gr * 256 + kc * 128;
      #pragma unroll
      for (int s = 0; s < 4; ++s) {
        u16x8 val = {0, 0, 0, 0, 0, 0, 0, 0};
        if (gr < N_NODES) val = *(const u16x8*)(src + (c4 + s) * 8);
        *(u16x8*)&Ab[r][(c4 + s) * 8] = val;
      }
    }
    {
      int r = tid >> 1, cb = (tid & 1) * 8;
      const ushort* src = Ws1t + ((size_t)h * 128 + r) * 256 + kc * 128;
      #pragma unroll
      for (int s = 0; s < 8; ++s)
        *(u16x8*)&Bb[r][(cb + s) * 8] = *(const u16x8*)(src + (cb + s) * 8);
    }
    __syncthreads();
    #pragma unroll
    for (int kk = 0; kk < 4; ++kk) {
      bf16x8 a = *(const bf16x8*)&Ab[wv * 16 + l15][kk * 32 + lhi * 8];
      #pragma unroll
      for (int nt = 0; nt < 8; ++nt) {
        bf16x8 b = *(const bf16x8*)&Bb[nt * 16 + l15][kk * 32 + lhi * 8];
        acc[nt] = __builtin_amdgcn_mfma_f32_16x16x32_bf16(a, b, acc[nt], 0, 0, 0);
      }
    }
    __syncthreads();
  }
  float part[4] = {0.f, 0.f, 0.f, 0.f};
  #pragma unroll
  for (int nt = 0; nt < 8; ++nt) {
    int c = h * 128 + nt * 16 + l15;
    float b1 = bs1[c], w2 = Ws2[c];
    #pragma unroll
    for (int j = 0; j < 4; ++j)
      part[j] += fmaxf(acc[nt][j] + b1, 0.f) * w2;
  }
  #pragma unroll
  for (int j = 0; j < 4; ++j) {
    #pragma unroll
    for (int o = 1; o < 16; o <<= 1) part[j] += __shfl_xor(part[j], o);
  }
  if (l15 == 0) {
    float b2 = bs2[h];
    #pragma unroll
    for (int j = 0; j < 4; ++j) {
      int row = base + wv * 16 + lhi * 4 + j;
      if (row < N_NODES) h0[(size_t)row * 8 + h] = part[j] + b2;
    }
  }
}

// ---------------- semantic channel QKV (MFMA) ----------------
// q written f32; k,v written bf16 (halves the k_gt gather traffic).

__global__ __launch_bounds__(256) void k_qkv_mfma(
    const ushort* __restrict__ Xb, const ushort* __restrict__ Wt,
    const float* __restrict__ bq, const float* __restrict__ bk,
    const float* __restrict__ bv, float* __restrict__ q,
    ushort* __restrict__ kb, ushort* __restrict__ vb) {
  __shared__ ushort Ab[64][136];
  __shared__ ushort Bb[128][136];
  int tid = threadIdx.x;
  int m = blockIdx.y >> 1, half = blockIdx.y & 1;
  int base = blockIdx.x * 64;
  int wv = tid >> 6, lane = tid & 63;
  int l15 = lane & 15, lhi = lane >> 4;
  f32x4 acc[8];
  #pragma unroll
  for (int nt = 0; nt < 8; ++nt) acc[nt] = (f32x4){0.f, 0.f, 0.f, 0.f};

  for (int kc = 0; kc < 2; ++kc) {
    {
      int r = tid >> 2, c4 = (tid & 3) * 4;
      int gr = base + r;
      const ushort* src = Xb + (size_t)gr * 256 + kc * 128;
      #pragma unroll
      for (int s = 0; s < 4; ++s) {
        u16x8 val = {0, 0, 0, 0, 0, 0, 0, 0};
        if (gr < N_NODES) val = *(const u16x8*)(src + (c4 + s) * 8);
        *(u16x8*)&Ab[r][(c4 + s) * 8] = val;
      }
    }
    {
      int r = tid >> 1, cb = (tid & 1) * 8;
      const ushort* src = Wt + (((size_t)m * 256 + half * 128 + r) * 256) + kc * 128;
      #pragma unroll
      for (int s = 0; s < 8; ++s)
        *(u16x8*)&Bb[r][(cb + s) * 8] = *(const u16x8*)(src + (cb + s) * 8);
    }
    __syncthreads();
    #pragma unroll
    for (int kk = 0; kk < 4; ++kk) {
      bf16x8 a = *(const bf16x8*)&Ab[wv * 16 + l15][kk * 32 + lhi * 8];
      #pragma unroll
      for (int nt = 0; nt < 8; ++nt) {
        bf16x8 b = *(const bf16x8*)&Bb[nt * 16 + l15][kk * 32 + lhi * 8];
        acc[nt] = __builtin_amdgcn_mfma_f32_16x16x32_bf16(a, b, acc[nt], 0, 0, 0);
      }
    }
    __syncthreads();
  }
  const float* bias = (m == 0) ? bq : (m == 1) ? bk : bv;
  #pragma unroll
  for (int nt = 0; nt < 8; ++nt) {
    int c = half * 128 + nt * 16 + l15;
    float bc = bias[c];
    #pragma unroll
    for (int j = 0; j < 4; ++j) {
      int row = base + wv * 16 + lhi * 4 + j;
      if (row < N_NODES) {
        float val = acc[nt][j] + bc;
        if (m == 0) q[(size_t)row * 256 + c] = val;
        else if (m == 1) kb[(size_t)row * 256 + c] = f2bf(val);
        else vb[(size_t)row * 256 + c] = f2bf(val);
      }
    }
  }
}

// ---------------- SA layers (wave per node: 8 heads x 8 edge-slots) ----------------

__global__ __launch_bounds__(256) void k_sa(const float* __restrict__ h_in,
                                            float* __restrict__ h_out,
                                            const int* __restrict__ rowPtr,
                                            const int* __restrict__ csrSrc,
                                            const int* __restrict__ csrType,
                                            const float* __restrict__ sa_w,
                                            const float* __restrict__ sa_al,
                                            const float* __restrict__ sa_ar,
                                            const float* __restrict__ saTab, int layer) {
  int node = blockIdx.x * 4 + (threadIdx.x >> 6);
  int lane = threadIdx.x & 63;
  int h = lane & 7, eslot = lane >> 3;
  float wgt = sa_w[layer * 8 + h];
  float al = sa_al[layer * 8 + h];
  float ar = sa_ar[layer * 8 + h];
  const float* tab = saTab + layer * 128;
  float zd = h_in[(size_t)node * 8 + h] * wgt;
  int s0 = rowPtr[node], s1 = rowPtr[node + 1];
  float m = -1e30f, lsum = 0.f, acc = 0.f;
  for (int i = s0 + eslot; i < s1; i += 8) {
    int s = csrSrc[i], ty = csrType[i];
    float zs = h_in[(size_t)s * 8 + h] * wgt;
    float e = zs * al + zd * ar + tab[ty * 8 + h];
    e = (e >= 0.f) ? e : 0.2f * e;
    float nm = fmaxf(m, e);
    float scl = expf(m - nm);
    float p = expf(e - nm);
    acc = acc * scl + p * zs;
    lsum = lsum * scl + p;
    m = nm;
  }
  // merge the 8 edge-slots (lanes differing in bits 3..5)
  #pragma unroll
  for (int off = 8; off < 64; off <<= 1) {
    float om = __shfl_xor(m, off);
    float ol = __shfl_xor(lsum, off);
    float oa = __shfl_xor(acc, off);
    float nm = fmaxf(m, om);
    float sl = expf(m - nm);
    float so = expf(om - nm);
    acc = acc * sl + oa * so;
    lsum = lsum * sl + ol * so;
    m = nm;
  }
  float o = acc / (lsum + 1e-9f);
  float r = o + zd;
  r = (r > 0.f) ? r : expm1f(r);
  if (layer == 0) {
    r += __shfl_xor(r, 1);
    r += __shfl_xor(r, 2);
    r += __shfl_xor(r, 4);
    r *= 0.125f;
  }
  if (eslot == 0) h_out[(size_t)node * 8 + h] = r;
}

// ---------------- GT edge phase (bf16 k/v gather, 2-edge unroll) ----------------

__global__ __launch_bounds__(256) void k_gt(const float* __restrict__ q,
                                            const ushort* __restrict__ kb,
                                            const ushort* __restrict__ vb,
                                            const float* __restrict__ epTab,
                                            const float* __restrict__ feats_sem,
                                            const int* __restrict__ rowPtr,
                                            const int* __restrict__ csrSrc,
                                            const int* __restrict__ csrType,
                                            float* __restrict__ agg) {
  int node = blockIdx.x * 4 + (threadIdx.x >> 6);
  int lane = threadIdx.x & 63;
  int c0 = lane * 4;
  const float SC = 0.17677669529663687f;  // 1/sqrt(32)
  float4 qv = *(const float4*)(q + (size_t)node * 256 + c0);
  qv.x *= SC; qv.y *= SC; qv.z *= SC; qv.w *= SC;
  float4 acc = {0.f, 0.f, 0.f, 0.f};
  float m = -1e30f, lsum = 0.f;
  int s0 = rowPtr[node], s1 = rowPtr[node + 1];
  int i = s0;
  for (; i + 1 < s1; i += 2) {
    int sA = csrSrc[i], tyA = csrType[i];
    int sB = csrSrc[i + 1], tyB = csrType[i + 1];
    // issue all 6 loads up front (MLP)
    ushort4 kA = *(const ushort4*)(kb + (size_t)sA * 256 + c0);
    ushort4 kB4 = *(const ushort4*)(kb + (size_t)sB * 256 + c0);
    float4 epA = *(const float4*)(epTab + tyA * 256 + c0);
    float4 epB = *(const float4*)(epTab + tyB * 256 + c0);
    ushort4 vA = *(const ushort4*)(vb + (size_t)sA * 256 + c0);
    ushort4 vB = *(const ushort4*)(vb + (size_t)sB * 256 + c0);
    float pA = qv.x * b2f(kA.x) * epA.x + qv.y * b2f(kA.y) * epA.y +
               qv.z * b2f(kA.z) * epA.z + qv.w * b2f(kA.w) * epA.w;
    float pB = qv.x * b2f(kB4.x) * epB.x + qv.y * b2f(kB4.y) * epB.y +
               qv.z * b2f(kB4.z) * epB.z + qv.w * b2f(kB4.w) * epB.w;
    pA += __shfl_xor(pA, 1); pB += __shfl_xor(pB, 1);
    pA += __shfl_xor(pA, 2); pB += __shfl_xor(pB, 2);
    pA += __shfl_xor(pA, 4); pB += __shfl_xor(pB, 4);
    float nm = fmaxf(m, fmaxf(pA, pB));
    float scl = expf(m - nm);
    float eA = expf(pA - nm);
    float eB = expf(pB - nm);
    acc.x = acc.x * scl + eA * b2f(vA.x) + eB * b2f(vB.x);
    acc.y = acc.y * scl + eA * b2f(vA.y) + eB * b2f(vB.y);
    acc.z = acc.z * scl + eA * b2f(vA.z) + eB * b2f(vB.z);
    acc.w = acc.w * scl + eA * b2f(vA.w) + eB * b2f(vB.w);
    lsum = lsum * scl + eA + eB;
    m = nm;
  }
  if (i < s1) {
    int s = csrSrc[i], ty = csrType[i];
    ushort4 kv = *(const ushort4*)(kb + (size_t)s * 256 + c0);
    float4 ep = *(const float4*)(epTab + ty * 256 + c0);
    ushort4 vv = *(const ushort4*)(vb + (size_t)s * 256 + c0);
    float part = qv.x * b2f(kv.x) * ep.x + qv.y * b2f(kv.y) * ep.y +
                 qv.z * b2f(kv.z) * ep.z + qv.w * b2f(kv.w) * ep.w;
    part += __shfl_xor(part, 1);
    part += __shfl_xor(part, 2);
    part += __shfl_xor(part, 4);
    float nm = fmaxf(m, part);
    float scl = expf(m - nm);
    float p = expf(part - nm);
    acc.x = acc.x * scl + p * b2f(vv.x);
    acc.y = acc.y * scl + p * b2f(vv.y);
    acc.z = acc.z * scl + p * b2f(vv.z);
    acc.w = acc.w * scl + p * b2f(vv.w);
    lsum = lsum * scl + p;
    m = nm;
  }
  float inv = 1.f / (lsum + 1e-9f);
  float4 fs = *(const float4*)(feats_sem + (size_t)node * 256 + c0);
  float4 r;
  r.x = acc.x * inv + fs.x;
  r.y = acc.y * inv + fs.y;
  r.z = acc.z * inv + fs.z;
  r.w = acc.w * inv + fs.w;
  *(float4*)(agg + (size_t)node * 256 + c0) = r;
}

__global__ void k_bnstats(const float* __restrict__ agg, double* __restrict__ colsum,
                          double* __restrict__ colssq) {
  int t = threadIdx.x;
  int r0 = blockIdx.x * 79;
  int r1 = min(r0 + 79, N_NODES);
  double s = 0.0, qq = 0.0;
  for (int r = r0; r < r1; ++r) {
    float x = agg[(size_t)r * 256 + t];
    s += (double)x;
    qq += (double)x * (double)x;
  }
  atomicAdd(&colsum[t], s);
  atomicAdd(&colssq[t], qq);
}

__global__ void k_bnfinal(const double* __restrict__ colsum, const double* __restrict__ colssq,
                          float* __restrict__ muArr, float* __restrict__ invArr) {
  int t = threadIdx.x;
  double mu = colsum[t] / (double)N_NODES;
  double var = colssq[t] / (double)N_NODES - mu * mu;
  muArr[t] = (float)mu;
  invArr[t] = (float)(1.0 / sqrt(var + 1e-5));
}

__global__ __launch_bounds__(256) void k_final(const float* __restrict__ agg,
                                               const float* __restrict__ muArr,
                                               const float* __restrict__ invArr,
                                               const float* __restrict__ bn_gamma,
                                               const float* __restrict__ bn_beta,
                                               const float* __restrict__ Wout,
                                               const float* __restrict__ bout,
                                               const float* __restrict__ hB,
                                               const float* __restrict__ cent,
                                               const float* __restrict__ gamma,
                                               const float* __restrict__ beta,
                                               float* __restrict__ out) {
  int node = blockIdx.x * 4 + (threadIdx.x >> 6);
  int lane = threadIdx.x & 63;
  int c0 = lane * 4;
  float4 x = *(const float4*)(agg + (size_t)node * 256 + c0);
  float4 mu = *(const float4*)(muArr + c0);
  float4 iv = *(const float4*)(invArr + c0);
  float4 g = *(const float4*)(bn_gamma + c0);
  float4 b = *(const float4*)(bn_beta + c0);
  float4 w = *(const float4*)(Wout + c0);
  float p = fmaxf((x.x - mu.x) * iv.x * g.x + b.x, 0.f) * w.x +
            fmaxf((x.y - mu.y) * iv.y * g.y + b.y, 0.f) * w.y +
            fmaxf((x.z - mu.z) * iv.z * g.z + b.z, 0.f) * w.z +
            fmaxf((x.w - mu.w) * iv.w * g.w + b.w, 0.f) * w.w;
  #pragma unroll
  for (int o = 1; o < 64; o <<= 1) p += __shfl_xor(p, o);
  float ls = p + bout[0];
  int h = lane & 7;
  float logit = 0.5f * hB[(size_t)node * 8 + h] + 0.5f * ls;
  float sc = (cent[node] * gamma[h] + beta[h]) * logit;
  sc += __shfl_xor(sc, 1);
  sc += __shfl_xor(sc, 2);
  sc += __shfl_xor(sc, 4);
  float mn = sc * 0.125f;
  mn = (mn >= 0.f) ? mn : 0.01f * mn;
  if (lane == 0) out[node] = mn;
}

// ---------------- launch ----------------

extern "C" void kernel_launch(void* const* d_in, const int* in_sizes, int n_in,
                              void* d_out, int out_size, void* d_ws, size_t ws_size,
                              hipStream_t stream) {
  (void)in_sizes; (void)n_in; (void)out_size; (void)ws_size;
  const float* feats_struct = (const float*)d_in[0];
  const float* feats_sem    = (const float*)d_in[1];
  const float* cent         = (const float*)d_in[2];
  const float* Ws1          = (const float*)d_in[3];
  const float* bs1          = (const float*)d_in[4];
  const float* Ws2          = (const float*)d_in[5];
  const float* bs2          = (const float*)d_in[6];
  const float* rel_emb      = (const float*)d_in[7];
  const float* sa_w         = (const float*)d_in[8];
  const float* sa_al        = (const float*)d_in[9];
  const float* sa_ar        = (const float*)d_in[10];
  const float* sa_We        = (const float*)d_in[11];
  const float* Wq           = (const float*)d_in[12];
  const float* bq           = (const float*)d_in[13];
  const float* Wk           = (const float*)d_in[14];
  const float* bk           = (const float*)d_in[15];
  const float* Wv           = (const float*)d_in[16];
  const float* bv           = (const float*)d_in[17];
  const float* We_gt        = (const float*)d_in[18];
  const float* bn_gamma     = (const float*)d_in[19];
  const float* bn_beta      = (const float*)d_in[20];
  const float* Wout         = (const float*)d_in[21];
  const float* bout         = (const float*)d_in[22];
  const float* gamma        = (const float*)d_in[23];
  const float* beta         = (const float*)d_in[24];
  const int* e_type         = (const int*)d_in[25];
  const int* e_src          = (const int*)d_in[26];
  const int* e_dst          = (const int*)d_in[27];
  float* out = (float*)d_out;

  char* wsb = (char*)d_ws;
  size_t off = 0;
  auto alloc = [&](size_t bytes) -> char* {
    char* p = wsb + off;
    off = (off + bytes + 255) & ~(size_t)255;
    return p;
  };
  float* saTab   = (float*)alloc(2 * 16 * 8 * 4);
  float* epTab   = (float*)alloc(16 * 256 * 4);
  int* deg       = (int*)alloc((size_t)N_NODES * 4);
  int* rowPtr    = (int*)alloc((size_t)(N_NODES + 1) * 4);
  int* cursor    = (int*)alloc((size_t)N_NODES * 4);
  int* csrSrc    = (int*)alloc((size_t)N_EDGES * 4);
  int* csrType   = (int*)alloc((size_t)N_EDGES * 4);
  float* h0      = (float*)alloc((size_t)N_NODES * 8 * 4);
  float* hA      = (float*)alloc((size_t)N_NODES * 8 * 4);
  float* hB      = (float*)alloc((size_t)N_NODES * 8 * 4);
  float* qb      = (float*)alloc((size_t)N_NODES * 256 * 4);
  ushort* kbB    = (ushort*)alloc((size_t)N_NODES * 256 * 2);
  ushort* vbB    = (ushort*)alloc((size_t)N_NODES * 256 * 2);
  float* agg     = (float*)alloc((size_t)N_NODES * 256 * 4);
  double* colsum = (double*)alloc(256 * 8);
  double* colssq = (double*)alloc(256 * 8);
  float* muArr   = (float*)alloc(256 * 4);
  float* invArr  = (float*)alloc(256 * 4);
  ushort* Xsb    = (ushort*)alloc((size_t)N_NODES * 256 * 2);
  ushort* Xmb    = (ushort*)alloc((size_t)N_NODES * 256 * 2);
  ushort* Ws1t   = (ushort*)alloc((size_t)8 * 128 * 256 * 2);
  ushort* Wqkvt  = (ushort*)alloc((size_t)3 * 256 * 256 * 2);

  hipMemsetAsync(deg, 0, (size_t)N_NODES * 4, stream);
  hipMemsetAsync(colsum, 0, 256 * 8, stream);
  hipMemsetAsync(colssq, 0, 256 * 8, stream);

  k_tables<<<1, 256, 0, stream>>>(rel_emb, sa_We, We_gt, saTab, epTab);
  k_hist<<<(N_EDGES + 255) / 256, 256, 0, stream>>>(e_dst, deg);
  k_scan<<<1, 256, 0, stream>>>(deg, rowPtr, cursor);
  k_fill<<<(N_EDGES + 255) / 256, 256, 0, stream>>>(e_dst, e_src, e_type, cursor, csrSrc, csrType);

  k_convX<<<N_NODES * 256 / (256 * 4), 256, 0, stream>>>(feats_struct, feats_sem, Xsb, Xmb);
  k_tws1<<<8 * 128, 256, 0, stream>>>(Ws1, Ws1t);
  k_twqkv<<<3 * 256, 256, 0, stream>>>(Wq, Wk, Wv, Wqkvt);

  const int MT = (N_NODES + 63) / 64;  // 313
  dim3 gMlp(MT, 8);
  k_mlp_mfma<<<gMlp, 256, 0, stream>>>(Xsb, Ws1t, bs1, Ws2, bs2, h0);
  k_sa<<<(N_NODES + 3) / 4, 256, 0, stream>>>(h0, hA, rowPtr, csrSrc, csrType,
                                              sa_w, sa_al, sa_ar, saTab, 0);
  k_sa<<<(N_NODES + 3) / 4, 256, 0, stream>>>(hA, hB, rowPtr, csrSrc, csrType,
                                              sa_w, sa_al, sa_ar, saTab, 1);

  dim3 gQkv(MT, 6);
  k_qkv_mfma<<<gQkv, 256, 0, stream>>>(Xmb, Wqkvt, bq, bk, bv, qb, kbB, vbB);
  k_gt<<<N_NODES / 4, 256, 0, stream>>>(qb, kbB, vbB, epTab, feats_sem,
                                        rowPtr, csrSrc, csrType, agg);
  k_bnstats<<<256, 256, 0, stream>>>(agg, colsum, colssq);
  k_bnfinal<<<1, 256, 0, stream>>>(colsum, colssq, muArr, invArr);
  k_final<<<N_NODES / 4, 256, 0, stream>>>(agg, muArr, invArr, bn_gamma, bn_beta,
                                           Wout, bout, hB, cent, gamma, beta, out);
}

// Round 6
// 367.124 us; speedup vs baseline: 3.6967x; 1.0949x over previous
//
#include <hip/hip_runtime.h>
#include <hip/hip_bf16.h>
#include <math.h>

#define N_NODES 20000
#define N_EDGES 256000
#define LOG2E 1.4426950408889634f

typedef __attribute__((ext_vector_type(8))) __bf16 bf16x8;
typedef __attribute__((ext_vector_type(8))) unsigned short u16x8;
typedef __attribute__((ext_vector_type(4))) float f32x4;

static __device__ __forceinline__ unsigned short f2bf(float f) {
  unsigned u = __float_as_uint(f);
  unsigned r = (u + 0x7fffu + ((u >> 16) & 1u)) >> 16;
  return (unsigned short)r;
}
static __device__ __forceinline__ float b2f(unsigned short u) {
  return __uint_as_float((unsigned)u << 16);
}

// ---------------- fused setup: tables | convX | tws1 | twqkv | hist ----------------
// segments: [0,1) tables, [1,5001) convX, [5001,6025) tws1, [6025,6793) twqkv,
//           [6793,7793) hist
__global__ __launch_bounds__(256) void k_setup(
    const float* __restrict__ rel_emb, const float* __restrict__ sa_We,
    const float* __restrict__ We_gt, const float* __restrict__ Xs,
    const float* __restrict__ Xm, const float* __restrict__ Ws1,
    const float* __restrict__ Wq, const float* __restrict__ Wk,
    const float* __restrict__ Wv, const int* __restrict__ e_dst,
    float* __restrict__ saTab, float* __restrict__ epTab,
    ushort* __restrict__ Xsb, ushort* __restrict__ Xmb,
    ushort* __restrict__ Ws1t, ushort* __restrict__ Wt,
    int* __restrict__ deg) {
  int b = blockIdx.x;
  int t = threadIdx.x;
  if (b == 0) {
    // saTab pre-scaled by LOG2E (only consumed inside exp2-domain scores)
    {
      int l = t >> 7, r = (t >> 3) & 15, h = t & 7;
      float acc = 0.f;
      for (int p = 0; p < 32; ++p)
        acc += rel_emb[r * 32 + p] * sa_We[l * 256 + p * 8 + h];
      saTab[t] = acc * LOG2E;
    }
    for (int r = 0; r < 16; ++r) {
      float acc = 0.f;
      for (int p = 0; p < 32; ++p)
        acc += rel_emb[r * 32 + p] * We_gt[p * 256 + t];
      epTab[r * 256 + t] = acc;
    }
  } else if (b < 5001) {
    size_t i = ((size_t)(b - 1) * 256 + t) * 4;
    float4 a = *(const float4*)(Xs + i);
    ushort4 ua = {f2bf(a.x), f2bf(a.y), f2bf(a.z), f2bf(a.w)};
    *(ushort4*)(Xsb + i) = ua;
    float4 c = *(const float4*)(Xm + i);
    ushort4 uc = {f2bf(c.x), f2bf(c.y), f2bf(c.z), f2bf(c.w)};
    *(ushort4*)(Xmb + i) = uc;
  } else if (b < 6025) {
    int lb = b - 5001;
    int h = lb >> 7, kcol = lb & 127;
    Ws1t[((size_t)h * 128 + kcol) * 256 + t] =
        f2bf(Ws1[((size_t)h * 256 + t) * 128 + kcol]);
  } else if (b < 6793) {
    int lb = b - 6025;
    int m = lb >> 8, n = lb & 255;
    const float* W = (m == 0) ? Wq : (m == 1) ? Wk : Wv;
    Wt[((size_t)m * 256 + n) * 256 + t] = f2bf(W[(size_t)t * 256 + n]);
  } else {
    int e = (b - 6793) * 256 + t;
    if (e < N_EDGES) atomicAdd(&deg[e_dst[e]], 1);
  }
}

__global__ __launch_bounds__(1024) void k_scan(const int* __restrict__ deg,
                                               int* __restrict__ rowPtr,
                                               int* __restrict__ cursor) {
  const int CH = (N_NODES + 1023) / 1024;  // 20
  int t = threadIdx.x;
  int b0 = t * CH, b1 = min(b0 + CH, N_NODES);
  int s = 0;
  for (int i = b0; i < b1; ++i) s += deg[i];
  __shared__ int part[1024];
  part[t] = s;
  __syncthreads();
  for (int off = 1; off < 1024; off <<= 1) {
    int add = (t >= off) ? part[t - off] : 0;
    __syncthreads();
    part[t] += add;
    __syncthreads();
  }
  int run = (t == 0) ? 0 : part[t - 1];
  for (int i = b0; i < b1; ++i) {
    rowPtr[i] = run;
    cursor[i] = run;
    run += deg[i];
  }
  if (t == 0) rowPtr[N_NODES] = part[1023];
}

__global__ void k_fill(const int* __restrict__ e_dst, const int* __restrict__ e_src,
                       const int* __restrict__ e_type, int* __restrict__ cursor,
                       int2* __restrict__ csrPack) {
  int e = blockIdx.x * 256 + threadIdx.x;
  if (e >= N_EDGES) return;
  int d = e_dst[e];
  int pos = atomicAdd(&cursor[d], 1);
  csrPack[pos] = make_int2(e_src[e], e_type[e]);
}

// ---------------- fused GEMM: y in [0,8) = MLP head y; y in [8,14) = QKV ----------------
// 64-node M-tile, 128-col N-tile, K=256 in 2 chunks of 128.
__global__ __launch_bounds__(256) void k_gemm(
    const ushort* __restrict__ Xsb, const ushort* __restrict__ Xmb,
    const ushort* __restrict__ Ws1t, const ushort* __restrict__ Wqkvt,
    const float* __restrict__ bs1, const float* __restrict__ Ws2,
    const float* __restrict__ bs2, const float* __restrict__ bq,
    const float* __restrict__ bk, const float* __restrict__ bv,
    float* __restrict__ h0, float* __restrict__ q, ushort* __restrict__ kvB) {
  __shared__ ushort Ab[64][136];
  __shared__ ushort Bb[128][136];
  int tid = threadIdx.x;
  int y = blockIdx.y;
  bool isMlp = (y < 8);
  int m = 0, half = 0;
  const ushort* Bsrc;
  const ushort* Xb;
  if (isMlp) {
    Xb = Xsb;
    Bsrc = Ws1t + (size_t)y * 128 * 256;
  } else {
    m = (y - 8) >> 1;
    half = (y - 8) & 1;
    Xb = Xmb;
    Bsrc = Wqkvt + ((size_t)m * 256 + half * 128) * 256;
  }
  int base = blockIdx.x * 64;
  int wv = tid >> 6, lane = tid & 63;
  int l15 = lane & 15, lhi = lane >> 4;
  f32x4 acc[8];
  #pragma unroll
  for (int nt = 0; nt < 8; ++nt) acc[nt] = (f32x4){0.f, 0.f, 0.f, 0.f};

  for (int kc = 0; kc < 2; ++kc) {
    {
      int r = tid >> 2, c4 = (tid & 3) * 4;
      int gr = base + r;
      const ushort* src = Xb + (size_t)gr * 256 + kc * 128;
      #pragma unroll
      for (int s = 0; s < 4; ++s) {
        u16x8 val = {0, 0, 0, 0, 0, 0, 0, 0};
        if (gr < N_NODES) val = *(const u16x8*)(src + (c4 + s) * 8);
        *(u16x8*)&Ab[r][(c4 + s) * 8] = val;
      }
    }
    {
      int r = tid >> 1, cb = (tid & 1) * 8;
      const ushort* src = Bsrc + (size_t)r * 256 + kc * 128;
      #pragma unroll
      for (int s = 0; s < 8; ++s)
        *(u16x8*)&Bb[r][(cb + s) * 8] = *(const u16x8*)(src + (cb + s) * 8);
    }
    __syncthreads();
    #pragma unroll
    for (int kk = 0; kk < 4; ++kk) {
      bf16x8 a = *(const bf16x8*)&Ab[wv * 16 + l15][kk * 32 + lhi * 8];
      #pragma unroll
      for (int nt = 0; nt < 8; ++nt) {
        bf16x8 b = *(const bf16x8*)&Bb[nt * 16 + l15][kk * 32 + lhi * 8];
        acc[nt] = __builtin_amdgcn_mfma_f32_16x16x32_bf16(a, b, acc[nt], 0, 0, 0);
      }
    }
    __syncthreads();
  }

  if (isMlp) {
    float part[4] = {0.f, 0.f, 0.f, 0.f};
    #pragma unroll
    for (int nt = 0; nt < 8; ++nt) {
      int c = y * 128 + nt * 16 + l15;
      float b1 = bs1[c], w2 = Ws2[c];
      #pragma unroll
      for (int j = 0; j < 4; ++j)
        part[j] += fmaxf(acc[nt][j] + b1, 0.f) * w2;
    }
    #pragma unroll
    for (int j = 0; j < 4; ++j) {
      #pragma unroll
      for (int o = 1; o < 16; o <<= 1) part[j] += __shfl_xor(part[j], o);
    }
    if (l15 == 0) {
      float b2 = bs2[y];
      #pragma unroll
      for (int j = 0; j < 4; ++j) {
        int row = base + wv * 16 + lhi * 4 + j;
        if (row < N_NODES) h0[(size_t)row * 8 + y] = part[j] + b2;
      }
    }
  } else {
    const float* bias = (m == 0) ? bq : (m == 1) ? bk : bv;
    #pragma unroll
    for (int nt = 0; nt < 8; ++nt) {
      int c = half * 128 + nt * 16 + l15;
      float bc = bias[c];
      #pragma unroll
      for (int j = 0; j < 4; ++j) {
        int row = base + wv * 16 + lhi * 4 + j;
        if (row < N_NODES) {
          float val = acc[nt][j] + bc;
          if (m == 0) q[(size_t)row * 256 + c] = val;
          else if (m == 1) kvB[(size_t)row * 512 + c] = f2bf(val);        // k half
          else kvB[(size_t)row * 512 + 256 + c] = f2bf(val);              // v half
        }
      }
    }
  }
}

// ---------------- SA layers (wave per node: 8 heads x 8 edge-slots, exp2 domain) ----------------

__global__ __launch_bounds__(256) void k_sa(const float* __restrict__ h_in,
                                            float* __restrict__ h_out,
                                            const int* __restrict__ rowPtr,
                                            const int2* __restrict__ csrPack,
                                            const float* __restrict__ sa_w,
                                            const float* __restrict__ sa_al,
                                            const float* __restrict__ sa_ar,
                                            const float* __restrict__ saTab, int layer) {
  int node = blockIdx.x * 4 + (threadIdx.x >> 6);
  int lane = threadIdx.x & 63;
  int h = lane & 7, eslot = lane >> 3;
  float wgt = sa_w[layer * 8 + h];
  float al2 = sa_al[layer * 8 + h] * LOG2E;
  float ar2 = sa_ar[layer * 8 + h] * LOG2E;
  const float* tab = saTab + layer * 128;  // pre-scaled by LOG2E
  float zd = h_in[(size_t)node * 8 + h] * wgt;
  int s0 = rowPtr[node], s1 = rowPtr[node + 1];
  float m = -1e30f, lsum = 0.f, acc = 0.f;
  for (int i = s0 + eslot; i < s1; i += 8) {
    int2 p = csrPack[i];
    float zs = h_in[(size_t)p.x * 8 + h] * wgt;
    float e = zs * al2 + zd * ar2 + tab[p.y * 8 + h];
    e = (e >= 0.f) ? e : 0.2f * e;
    float nm = fmaxf(m, e);
    float scl = exp2f(m - nm);
    float pw = exp2f(e - nm);
    acc = acc * scl + pw * zs;
    lsum = lsum * scl + pw;
    m = nm;
  }
  #pragma unroll
  for (int off = 8; off < 64; off <<= 1) {
    float om = __shfl_xor(m, off);
    float ol = __shfl_xor(lsum, off);
    float oa = __shfl_xor(acc, off);
    float nm = fmaxf(m, om);
    float sl = exp2f(m - nm);
    float so = exp2f(om - nm);
    acc = acc * sl + oa * so;
    lsum = lsum * sl + ol * so;
    m = nm;
  }
  float o = acc / (lsum + 1e-9f);
  float r = o + zd;
  r = (r > 0.f) ? r : expm1f(r);
  if (layer == 0) {
    r += __shfl_xor(r, 1);
    r += __shfl_xor(r, 2);
    r += __shfl_xor(r, 4);
    r *= 0.125f;
  }
  if (eslot == 0) h_out[(size_t)node * 8 + h] = r;
}

// ---------------- GT edge phase (interleaved bf16 kv gather, exp2 domain) ----------------

__global__ __launch_bounds__(256) void k_gt(const float* __restrict__ q,
                                            const ushort* __restrict__ kvB,
                                            const float* __restrict__ epTab,
                                            const float* __restrict__ feats_sem,
                                            const int* __restrict__ rowPtr,
                                            const int2* __restrict__ csrPack,
                                            ushort* __restrict__ agg) {
  int node = blockIdx.x * 4 + (threadIdx.x >> 6);
  int lane = threadIdx.x & 63;
  int c0 = lane * 4;
  const float SC2 = 0.17677669529663687f * LOG2E;  // 1/sqrt(32) * log2(e)
  float4 qv = *(const float4*)(q + (size_t)node * 256 + c0);
  qv.x *= SC2; qv.y *= SC2; qv.z *= SC2; qv.w *= SC2;
  float4 acc = {0.f, 0.f, 0.f, 0.f};
  float m = -1e30f, lsum = 0.f;
  int s0 = rowPtr[node], s1 = rowPtr[node + 1];
  int i = s0;
  for (; i + 1 < s1; i += 2) {
    int2 eA = csrPack[i], eB = csrPack[i + 1];
    const ushort* rA = kvB + (size_t)eA.x * 512 + c0;
    const ushort* rB = kvB + (size_t)eB.x * 512 + c0;
    ushort4 kA = *(const ushort4*)rA;
    ushort4 kB4 = *(const ushort4*)rB;
    float4 epA = *(const float4*)(epTab + eA.y * 256 + c0);
    float4 epB = *(const float4*)(epTab + eB.y * 256 + c0);
    ushort4 vA = *(const ushort4*)(rA + 256);
    ushort4 vB = *(const ushort4*)(rB + 256);
    float pA = qv.x * b2f(kA.x) * epA.x + qv.y * b2f(kA.y) * epA.y +
               qv.z * b2f(kA.z) * epA.z + qv.w * b2f(kA.w) * epA.w;
    float pB = qv.x * b2f(kB4.x) * epB.x + qv.y * b2f(kB4.y) * epB.y +
               qv.z * b2f(kB4.z) * epB.z + qv.w * b2f(kB4.w) * epB.w;
    pA += __shfl_xor(pA, 1); pB += __shfl_xor(pB, 1);
    pA += __shfl_xor(pA, 2); pB += __shfl_xor(pB, 2);
    pA += __shfl_xor(pA, 4); pB += __shfl_xor(pB, 4);
    float nm = fmaxf(m, fmaxf(pA, pB));
    float scl = exp2f(m - nm);
    float wA = exp2f(pA - nm);
    float wB = exp2f(pB - nm);
    acc.x = acc.x * scl + wA * b2f(vA.x) + wB * b2f(vB.x);
    acc.y = acc.y * scl + wA * b2f(vA.y) + wB * b2f(vB.y);
    acc.z = acc.z * scl + wA * b2f(vA.z) + wB * b2f(vB.z);
    acc.w = acc.w * scl + wA * b2f(vA.w) + wB * b2f(vB.w);
    lsum = lsum * scl + wA + wB;
    m = nm;
  }
  if (i < s1) {
    int2 eA = csrPack[i];
    const ushort* rA = kvB + (size_t)eA.x * 512 + c0;
    ushort4 kv = *(const ushort4*)rA;
    float4 ep = *(const float4*)(epTab + eA.y * 256 + c0);
    ushort4 vv = *(const ushort4*)(rA + 256);
    float part = qv.x * b2f(kv.x) * ep.x + qv.y * b2f(kv.y) * ep.y +
                 qv.z * b2f(kv.z) * ep.z + qv.w * b2f(kv.w) * ep.w;
    part += __shfl_xor(part, 1);
    part += __shfl_xor(part, 2);
    part += __shfl_xor(part, 4);
    float nm = fmaxf(m, part);
    float scl = exp2f(m - nm);
    float pw = exp2f(part - nm);
    acc.x = acc.x * scl + pw * b2f(vv.x);
    acc.y = acc.y * scl + pw * b2f(vv.y);
    acc.z = acc.z * scl + pw * b2f(vv.z);
    acc.w = acc.w * scl + pw * b2f(vv.w);
    lsum = lsum * scl + pw;
    m = nm;
  }
  float inv = 1.f / (lsum + 1e-9f);
  float4 fs = *(const float4*)(feats_sem + (size_t)node * 256 + c0);
  ushort4 r;
  r.x = f2bf(acc.x * inv + fs.x);
  r.y = f2bf(acc.y * inv + fs.y);
  r.z = f2bf(acc.z * inv + fs.z);
  r.w = f2bf(acc.w * inv + fs.w);
  *(ushort4*)(agg + (size_t)node * 256 + c0) = r;
}

__global__ void k_bnstats(const ushort* __restrict__ agg, double* __restrict__ colsum,
                          double* __restrict__ colssq) {
  int t = threadIdx.x;
  int r0 = blockIdx.x * 79;
  int r1 = min(r0 + 79, N_NODES);
  double s = 0.0, qq = 0.0;
  for (int r = r0; r < r1; ++r) {
    float x = b2f(agg[(size_t)r * 256 + t]);
    s += (double)x;
    qq += (double)x * (double)x;
  }
  atomicAdd(&colsum[t], s);
  atomicAdd(&colssq[t], qq);
}

__global__ void k_bnfinal(const double* __restrict__ colsum, const double* __restrict__ colssq,
                          float* __restrict__ muArr, float* __restrict__ invArr) {
  int t = threadIdx.x;
  double mu = colsum[t] / (double)N_NODES;
  double var = colssq[t] / (double)N_NODES - mu * mu;
  muArr[t] = (float)mu;
  invArr[t] = (float)(1.0 / sqrt(var + 1e-5));
}

__global__ __launch_bounds__(256) void k_final(const ushort* __restrict__ agg,
                                               const float* __restrict__ muArr,
                                               const float* __restrict__ invArr,
                                               const float* __restrict__ bn_gamma,
                                               const float* __restrict__ bn_beta,
                                               const float* __restrict__ Wout,
                                               const float* __restrict__ bout,
                                               const float* __restrict__ hB,
                                               const float* __restrict__ cent,
                                               const float* __restrict__ gamma,
                                               const float* __restrict__ beta,
                                               float* __restrict__ out) {
  int node = blockIdx.x * 4 + (threadIdx.x >> 6);
  int lane = threadIdx.x & 63;
  int c0 = lane * 4;
  ushort4 xa = *(const ushort4*)(agg + (size_t)node * 256 + c0);
  float4 mu = *(const float4*)(muArr + c0);
  float4 iv = *(const float4*)(invArr + c0);
  float4 g = *(const float4*)(bn_gamma + c0);
  float4 b = *(const float4*)(bn_beta + c0);
  float4 w = *(const float4*)(Wout + c0);
  float p = fmaxf((b2f(xa.x) - mu.x) * iv.x * g.x + b.x, 0.f) * w.x +
            fmaxf((b2f(xa.y) - mu.y) * iv.y * g.y + b.y, 0.f) * w.y +
            fmaxf((b2f(xa.z) - mu.z) * iv.z * g.z + b.z, 0.f) * w.z +
            fmaxf((b2f(xa.w) - mu.w) * iv.w * g.w + b.w, 0.f) * w.w;
  #pragma unroll
  for (int o = 1; o < 64; o <<= 1) p += __shfl_xor(p, o);
  float ls = p + bout[0];
  int h = lane & 7;
  float logit = 0.5f * hB[(size_t)node * 8 + h] + 0.5f * ls;
  float sc = (cent[node] * gamma[h] + beta[h]) * logit;
  sc += __shfl_xor(sc, 1);
  sc += __shfl_xor(sc, 2);
  sc += __shfl_xor(sc, 4);
  float mn = sc * 0.125f;
  mn = (mn >= 0.f) ? mn : 0.01f * mn;
  if (lane == 0) out[node] = mn;
}

// ---------------- launch ----------------

extern "C" void kernel_launch(void* const* d_in, const int* in_sizes, int n_in,
                              void* d_out, int out_size, void* d_ws, size_t ws_size,
                              hipStream_t stream) {
  (void)in_sizes; (void)n_in; (void)out_size; (void)ws_size;
  const float* feats_struct = (const float*)d_in[0];
  const float* feats_sem    = (const float*)d_in[1];
  const float* cent         = (const float*)d_in[2];
  const float* Ws1          = (const float*)d_in[3];
  const float* bs1          = (const float*)d_in[4];
  const float* Ws2          = (const float*)d_in[5];
  const float* bs2          = (const float*)d_in[6];
  const float* rel_emb      = (const float*)d_in[7];
  const float* sa_w         = (const float*)d_in[8];
  const float* sa_al        = (const float*)d_in[9];
  const float* sa_ar        = (const float*)d_in[10];
  const float* sa_We        = (const float*)d_in[11];
  const float* Wq           = (const float*)d_in[12];
  const float* bq           = (const float*)d_in[13];
  const float* Wk           = (const float*)d_in[14];
  const float* bk           = (const float*)d_in[15];
  const float* Wv           = (const float*)d_in[16];
  const float* bv           = (const float*)d_in[17];
  const float* We_gt        = (const float*)d_in[18];
  const float* bn_gamma     = (const float*)d_in[19];
  const float* bn_beta      = (const float*)d_in[20];
  const float* Wout         = (const float*)d_in[21];
  const float* bout         = (const float*)d_in[22];
  const float* gamma        = (const float*)d_in[23];
  const float* beta         = (const float*)d_in[24];
  const int* e_type         = (const int*)d_in[25];
  const int* e_src          = (const int*)d_in[26];
  const int* e_dst          = (const int*)d_in[27];
  float* out = (float*)d_out;

  char* wsb = (char*)d_ws;
  size_t off = 0;
  auto alloc = [&](size_t bytes) -> char* {
    char* p = wsb + off;
    off = (off + bytes + 255) & ~(size_t)255;
    return p;
  };
  float* saTab   = (float*)alloc(2 * 16 * 8 * 4);
  float* epTab   = (float*)alloc(16 * 256 * 4);
  int* deg       = (int*)alloc((size_t)N_NODES * 4);
  int* rowPtr    = (int*)alloc((size_t)(N_NODES + 1) * 4);
  int* cursor    = (int*)alloc((size_t)N_NODES * 4);
  int2* csrPack  = (int2*)alloc((size_t)N_EDGES * 8);
  float* h0      = (float*)alloc((size_t)N_NODES * 8 * 4);
  float* hA      = (float*)alloc((size_t)N_NODES * 8 * 4);
  float* hB      = (float*)alloc((size_t)N_NODES * 8 * 4);
  float* qb      = (float*)alloc((size_t)N_NODES * 256 * 4);
  ushort* kvB    = (ushort*)alloc((size_t)N_NODES * 512 * 2);
  ushort* agg    = (ushort*)alloc((size_t)N_NODES * 256 * 2);
  double* colsum = (double*)alloc(256 * 8);
  double* colssq = (double*)alloc(256 * 8);
  float* muArr   = (float*)alloc(256 * 4);
  float* invArr  = (float*)alloc(256 * 4);
  ushort* Xsb    = (ushort*)alloc((size_t)N_NODES * 256 * 2);
  ushort* Xmb    = (ushort*)alloc((size_t)N_NODES * 256 * 2);
  ushort* Ws1t   = (ushort*)alloc((size_t)8 * 128 * 256 * 2);
  ushort* Wqkvt  = (ushort*)alloc((size_t)3 * 256 * 256 * 2);

  hipMemsetAsync(deg, 0, (size_t)N_NODES * 4, stream);
  hipMemsetAsync(colsum, 0, 256 * 8, stream);
  hipMemsetAsync(colssq, 0, 256 * 8, stream);

  k_setup<<<7793, 256, 0, stream>>>(rel_emb, sa_We, We_gt, feats_struct, feats_sem,
                                    Ws1, Wq, Wk, Wv, e_dst,
                                    saTab, epTab, Xsb, Xmb, Ws1t, Wqkvt, deg);
  k_scan<<<1, 1024, 0, stream>>>(deg, rowPtr, cursor);
  k_fill<<<(N_EDGES + 255) / 256, 256, 0, stream>>>(e_dst, e_src, e_type, cursor, csrPack);

  const int MT = (N_NODES + 63) / 64;  // 313
  dim3 gGemm(MT, 14);
  k_gemm<<<gGemm, 256, 0, stream>>>(Xsb, Xmb, Ws1t, Wqkvt, bs1, Ws2, bs2,
                                    bq, bk, bv, h0, qb, kvB);
  k_sa<<<(N_NODES + 3) / 4, 256, 0, stream>>>(h0, hA, rowPtr, csrPack,
                                              sa_w, sa_al, sa_ar, saTab, 0);
  k_sa<<<(N_NODES + 3) / 4, 256, 0, stream>>>(hA, hB, rowPtr, csrPack,
                                              sa_w, sa_al, sa_ar, saTab, 1);
  k_gt<<<N_NODES / 4, 256, 0, stream>>>(qb, kvB, epTab, feats_sem,
                                        rowPtr, csrPack, agg);
  k_bnstats<<<256, 256, 0, stream>>>(agg, colsum, colssq);
  k_bnfinal<<<1, 256, 0, stream>>>(colsum, colssq, muArr, invArr);
  k_final<<<N_NODES / 4, 256, 0, stream>>>(agg, muArr, invArr, bn_gamma, bn_beta,
                                           Wout, bout, hB, cent, gamma, beta, out);
}

// Round 7
// 363.933 us; speedup vs baseline: 3.7291x; 1.0088x over previous
//
#include <hip/hip_runtime.h>
#include <hip/hip_bf16.h>
#include <math.h>

#define N_NODES 20000
#define N_EDGES 256000
#define LOG2E 1.4426950408889634f

typedef __attribute__((ext_vector_type(8))) __bf16 bf16x8;
typedef __attribute__((ext_vector_type(8))) unsigned short u16x8;
typedef __attribute__((ext_vector_type(4))) float f32x4;

static __device__ __forceinline__ unsigned short f2bf(float f) {
  unsigned u = __float_as_uint(f);
  unsigned r = (u + 0x7fffu + ((u >> 16) & 1u)) >> 16;
  return (unsigned short)r;
}
static __device__ __forceinline__ float b2f(unsigned short u) {
  return __uint_as_float((unsigned)u << 16);
}

// ---------------- fused setup: tables | convX | tws1 | twqkv | hist ----------------
__global__ __launch_bounds__(256) void k_setup(
    const float* __restrict__ rel_emb, const float* __restrict__ sa_We,
    const float* __restrict__ We_gt, const float* __restrict__ Xs,
    const float* __restrict__ Xm, const float* __restrict__ Ws1,
    const float* __restrict__ Wq, const float* __restrict__ Wk,
    const float* __restrict__ Wv, const int* __restrict__ e_dst,
    float* __restrict__ saTab, float* __restrict__ epTab,
    ushort* __restrict__ Xsb, ushort* __restrict__ Xmb,
    ushort* __restrict__ Ws1t, ushort* __restrict__ Wt,
    int* __restrict__ deg) {
  int b = blockIdx.x;
  int t = threadIdx.x;
  if (b == 0) {
    {
      int l = t >> 7, r = (t >> 3) & 15, h = t & 7;
      float acc = 0.f;
      for (int p = 0; p < 32; ++p)
        acc += rel_emb[r * 32 + p] * sa_We[l * 256 + p * 8 + h];
      saTab[t] = acc * LOG2E;
    }
    for (int r = 0; r < 16; ++r) {
      float acc = 0.f;
      for (int p = 0; p < 32; ++p)
        acc += rel_emb[r * 32 + p] * We_gt[p * 256 + t];
      epTab[r * 256 + t] = acc;
    }
  } else if (b < 5001) {
    size_t i = ((size_t)(b - 1) * 256 + t) * 4;
    float4 a = *(const float4*)(Xs + i);
    ushort4 ua = {f2bf(a.x), f2bf(a.y), f2bf(a.z), f2bf(a.w)};
    *(ushort4*)(Xsb + i) = ua;
    float4 c = *(const float4*)(Xm + i);
    ushort4 uc = {f2bf(c.x), f2bf(c.y), f2bf(c.z), f2bf(c.w)};
    *(ushort4*)(Xmb + i) = uc;
  } else if (b < 6025) {
    int lb = b - 5001;
    int h = lb >> 7, kcol = lb & 127;
    Ws1t[((size_t)h * 128 + kcol) * 256 + t] =
        f2bf(Ws1[((size_t)h * 256 + t) * 128 + kcol]);
  } else if (b < 6793) {
    int lb = b - 6025;
    int m = lb >> 8, n = lb & 255;
    const float* W = (m == 0) ? Wq : (m == 1) ? Wk : Wv;
    Wt[((size_t)m * 256 + n) * 256 + t] = f2bf(W[(size_t)t * 256 + n]);
  } else {
    int e = (b - 6793) * 256 + t;
    if (e < N_EDGES) atomicAdd(&deg[e_dst[e]], 1);
  }
}

__global__ __launch_bounds__(1024) void k_scan(const int* __restrict__ deg,
                                               int* __restrict__ rowPtr,
                                               int* __restrict__ cursor) {
  const int CH = (N_NODES + 1023) / 1024;  // 20
  int t = threadIdx.x;
  int b0 = t * CH, b1 = min(b0 + CH, N_NODES);
  int s = 0;
  for (int i = b0; i < b1; ++i) s += deg[i];
  __shared__ int part[1024];
  part[t] = s;
  __syncthreads();
  for (int off = 1; off < 1024; off <<= 1) {
    int add = (t >= off) ? part[t - off] : 0;
    __syncthreads();
    part[t] += add;
    __syncthreads();
  }
  int run = (t == 0) ? 0 : part[t - 1];
  for (int i = b0; i < b1; ++i) {
    rowPtr[i] = run;
    cursor[i] = run;
    run += deg[i];
  }
  if (t == 0) rowPtr[N_NODES] = part[1023];
}

__global__ void k_fill(const int* __restrict__ e_dst, const int* __restrict__ e_src,
                       const int* __restrict__ e_type, int* __restrict__ cursor,
                       int2* __restrict__ csrPack) {
  int e = blockIdx.x * 256 + threadIdx.x;
  if (e >= N_EDGES) return;
  int d = e_dst[e];
  int pos = atomicAdd(&cursor[d], 1);
  csrPack[pos] = make_int2(e_src[e], e_type[e]);
}

// ---------------- fused GEMM, 128x128 tile, XOR-swizzled LDS ----------------
// y in [0,8) = MLP head y; y in [8,14) = QKV slice.
__global__ __launch_bounds__(256) void k_gemm(
    const ushort* __restrict__ Xsb, const ushort* __restrict__ Xmb,
    const ushort* __restrict__ Ws1t, const ushort* __restrict__ Wqkvt,
    const float* __restrict__ bs1, const float* __restrict__ Ws2,
    const float* __restrict__ bs2, const float* __restrict__ bq,
    const float* __restrict__ bk, const float* __restrict__ bv,
    float* __restrict__ h0, float* __restrict__ q, ushort* __restrict__ kvB) {
  __shared__ ushort Ab[128][128];  // swizzled: elem col ^= (row&7)<<3
  __shared__ ushort Bb[128][128];
  int tid = threadIdx.x;
  int y = blockIdx.y;
  bool isMlp = (y < 8);
  int m = 0, half = 0;
  const ushort* Bsrc;
  const ushort* Xb;
  if (isMlp) {
    Xb = Xsb;
    Bsrc = Ws1t + (size_t)y * 128 * 256;
  } else {
    m = (y - 8) >> 1;
    half = (y - 8) & 1;
    Xb = Xmb;
    Bsrc = Wqkvt + ((size_t)m * 256 + half * 128) * 256;
  }
  int base = blockIdx.x * 128;
  int wv = tid >> 6, lane = tid & 63;
  int l15 = lane & 15, lhi = lane >> 4;
  int rs = tid >> 4;          // 0..15
  int cs = (tid & 15) * 8;    // element col 0..120
  f32x4 acc[2][8];
  #pragma unroll
  for (int mr = 0; mr < 2; ++mr)
    #pragma unroll
    for (int nt = 0; nt < 8; ++nt) acc[mr][nt] = (f32x4){0.f, 0.f, 0.f, 0.f};

  for (int kc = 0; kc < 2; ++kc) {
    #pragma unroll
    for (int s = 0; s < 8; ++s) {
      int r = rs + s * 16;
      int csw = cs ^ ((r & 7) << 3);
      int gr = base + r;
      u16x8 val = {0, 0, 0, 0, 0, 0, 0, 0};
      if (gr < N_NODES) val = *(const u16x8*)(Xb + (size_t)gr * 256 + kc * 128 + cs);
      *(u16x8*)&Ab[r][csw] = val;
    }
    #pragma unroll
    for (int s = 0; s < 8; ++s) {
      int r = rs + s * 16;
      int csw = cs ^ ((r & 7) << 3);
      *(u16x8*)&Bb[r][csw] = *(const u16x8*)(Bsrc + (size_t)r * 256 + kc * 128 + cs);
    }
    __syncthreads();
    int swzA = (l15 & 7) << 3;
    #pragma unroll
    for (int kk = 0; kk < 4; ++kk) {
      int col = (kk * 32 + lhi * 8);
      bf16x8 a0 = *(const bf16x8*)&Ab[wv * 32 + l15][col ^ swzA];
      bf16x8 a1 = *(const bf16x8*)&Ab[wv * 32 + 16 + l15][col ^ swzA];
      #pragma unroll
      for (int nt = 0; nt < 8; ++nt) {
        bf16x8 b = *(const bf16x8*)&Bb[nt * 16 + l15][col ^ swzA];
        acc[0][nt] = __builtin_amdgcn_mfma_f32_16x16x32_bf16(a0, b, acc[0][nt], 0, 0, 0);
        acc[1][nt] = __builtin_amdgcn_mfma_f32_16x16x32_bf16(a1, b, acc[1][nt], 0, 0, 0);
      }
    }
    __syncthreads();
  }

  if (isMlp) {
    float part[2][4] = {{0.f, 0.f, 0.f, 0.f}, {0.f, 0.f, 0.f, 0.f}};
    #pragma unroll
    for (int nt = 0; nt < 8; ++nt) {
      int c = y * 128 + nt * 16 + l15;
      float b1 = bs1[c], w2 = Ws2[c];
      #pragma unroll
      for (int mr = 0; mr < 2; ++mr)
        #pragma unroll
        for (int j = 0; j < 4; ++j)
          part[mr][j] += fmaxf(acc[mr][nt][j] + b1, 0.f) * w2;
    }
    #pragma unroll
    for (int mr = 0; mr < 2; ++mr)
      #pragma unroll
      for (int j = 0; j < 4; ++j) {
        #pragma unroll
        for (int o = 1; o < 16; o <<= 1) part[mr][j] += __shfl_xor(part[mr][j], o);
      }
    if (l15 == 0) {
      float b2 = bs2[y];
      #pragma unroll
      for (int mr = 0; mr < 2; ++mr)
        #pragma unroll
        for (int j = 0; j < 4; ++j) {
          int row = base + wv * 32 + mr * 16 + lhi * 4 + j;
          if (row < N_NODES) h0[(size_t)row * 8 + y] = part[mr][j] + b2;
        }
    }
  } else {
    const float* bias = (m == 0) ? bq : (m == 1) ? bk : bv;
    #pragma unroll
    for (int nt = 0; nt < 8; ++nt) {
      int c = half * 128 + nt * 16 + l15;
      float bc = bias[c];
      #pragma unroll
      for (int mr = 0; mr < 2; ++mr)
        #pragma unroll
        for (int j = 0; j < 4; ++j) {
          int row = base + wv * 32 + mr * 16 + lhi * 4 + j;
          if (row < N_NODES) {
            float val = acc[mr][nt][j] + bc;
            if (m == 0) q[(size_t)row * 256 + c] = val;
            else if (m == 1) kvB[(size_t)row * 512 + c] = f2bf(val);
            else kvB[(size_t)row * 512 + 256 + c] = f2bf(val);
          }
        }
    }
  }
}

// ---------------- SA layers (wave per node: 8 heads x 8 edge-slots, exp2 domain) ----------------

__global__ __launch_bounds__(256) void k_sa(const float* __restrict__ h_in,
                                            float* __restrict__ h_out,
                                            const int* __restrict__ rowPtr,
                                            const int2* __restrict__ csrPack,
                                            const float* __restrict__ sa_w,
                                            const float* __restrict__ sa_al,
                                            const float* __restrict__ sa_ar,
                                            const float* __restrict__ saTab, int layer) {
  int node = blockIdx.x * 4 + (threadIdx.x >> 6);
  int lane = threadIdx.x & 63;
  int h = lane & 7, eslot = lane >> 3;
  float wgt = sa_w[layer * 8 + h];
  float al2 = sa_al[layer * 8 + h] * LOG2E;
  float ar2 = sa_ar[layer * 8 + h] * LOG2E;
  const float* tab = saTab + layer * 128;
  float zd = h_in[(size_t)node * 8 + h] * wgt;
  int s0 = rowPtr[node], s1 = rowPtr[node + 1];
  float m = -1e30f, lsum = 0.f, acc = 0.f;
  for (int i = s0 + eslot; i < s1; i += 8) {
    int2 p = csrPack[i];
    float zs = h_in[(size_t)p.x * 8 + h] * wgt;
    float e = zs * al2 + zd * ar2 + tab[p.y * 8 + h];
    e = (e >= 0.f) ? e : 0.2f * e;
    float nm = fmaxf(m, e);
    float scl = exp2f(m - nm);
    float pw = exp2f(e - nm);
    acc = acc * scl + pw * zs;
    lsum = lsum * scl + pw;
    m = nm;
  }
  #pragma unroll
  for (int off = 8; off < 64; off <<= 1) {
    float om = __shfl_xor(m, off);
    float ol = __shfl_xor(lsum, off);
    float oa = __shfl_xor(acc, off);
    float nm = fmaxf(m, om);
    float sl = exp2f(m - nm);
    float so = exp2f(om - nm);
    acc = acc * sl + oa * so;
    lsum = lsum * sl + ol * so;
    m = nm;
  }
  float o = acc / (lsum + 1e-9f);
  float r = o + zd;
  r = (r > 0.f) ? r : expm1f(r);
  if (layer == 0) {
    r += __shfl_xor(r, 1);
    r += __shfl_xor(r, 2);
    r += __shfl_xor(r, 4);
    r *= 0.125f;
  }
  if (eslot == 0) h_out[(size_t)node * 8 + h] = r;
}

// ---------------- GT edge phase (interleaved bf16 kv gather, exp2 domain) ----------------

__global__ __launch_bounds__(256) void k_gt(const float* __restrict__ q,
                                            const ushort* __restrict__ kvB,
                                            const float* __restrict__ epTab,
                                            const float* __restrict__ feats_sem,
                                            const int* __restrict__ rowPtr,
                                            const int2* __restrict__ csrPack,
                                            ushort* __restrict__ agg) {
  int node = blockIdx.x * 4 + (threadIdx.x >> 6);
  int lane = threadIdx.x & 63;
  int c0 = lane * 4;
  const float SC2 = 0.17677669529663687f * LOG2E;
  float4 qv = *(const float4*)(q + (size_t)node * 256 + c0);
  qv.x *= SC2; qv.y *= SC2; qv.z *= SC2; qv.w *= SC2;
  float4 acc = {0.f, 0.f, 0.f, 0.f};
  float m = -1e30f, lsum = 0.f;
  int s0 = rowPtr[node], s1 = rowPtr[node + 1];
  int i = s0;
  for (; i + 1 < s1; i += 2) {
    int2 eA = csrPack[i], eB = csrPack[i + 1];
    const ushort* rA = kvB + (size_t)eA.x * 512 + c0;
    const ushort* rB = kvB + (size_t)eB.x * 512 + c0;
    ushort4 kA = *(const ushort4*)rA;
    ushort4 kB4 = *(const ushort4*)rB;
    float4 epA = *(const float4*)(epTab + eA.y * 256 + c0);
    float4 epB = *(const float4*)(epTab + eB.y * 256 + c0);
    ushort4 vA = *(const ushort4*)(rA + 256);
    ushort4 vB = *(const ushort4*)(rB + 256);
    float pA = qv.x * b2f(kA.x) * epA.x + qv.y * b2f(kA.y) * epA.y +
               qv.z * b2f(kA.z) * epA.z + qv.w * b2f(kA.w) * epA.w;
    float pB = qv.x * b2f(kB4.x) * epB.x + qv.y * b2f(kB4.y) * epB.y +
               qv.z * b2f(kB4.z) * epB.z + qv.w * b2f(kB4.w) * epB.w;
    pA += __shfl_xor(pA, 1); pB += __shfl_xor(pB, 1);
    pA += __shfl_xor(pA, 2); pB += __shfl_xor(pB, 2);
    pA += __shfl_xor(pA, 4); pB += __shfl_xor(pB, 4);
    float nm = fmaxf(m, fmaxf(pA, pB));
    float scl = exp2f(m - nm);
    float wA = exp2f(pA - nm);
    float wB = exp2f(pB - nm);
    acc.x = acc.x * scl + wA * b2f(vA.x) + wB * b2f(vB.x);
    acc.y = acc.y * scl + wA * b2f(vA.y) + wB * b2f(vB.y);
    acc.z = acc.z * scl + wA * b2f(vA.z) + wB * b2f(vB.z);
    acc.w = acc.w * scl + wA * b2f(vA.w) + wB * b2f(vB.w);
    lsum = lsum * scl + wA + wB;
    m = nm;
  }
  if (i < s1) {
    int2 eA = csrPack[i];
    const ushort* rA = kvB + (size_t)eA.x * 512 + c0;
    ushort4 kv = *(const ushort4*)rA;
    float4 ep = *(const float4*)(epTab + eA.y * 256 + c0);
    ushort4 vv = *(const ushort4*)(rA + 256);
    float part = qv.x * b2f(kv.x) * ep.x + qv.y * b2f(kv.y) * ep.y +
                 qv.z * b2f(kv.z) * ep.z + qv.w * b2f(kv.w) * ep.w;
    part += __shfl_xor(part, 1);
    part += __shfl_xor(part, 2);
    part += __shfl_xor(part, 4);
    float nm = fmaxf(m, part);
    float scl = exp2f(m - nm);
    float pw = exp2f(part - nm);
    acc.x = acc.x * scl + pw * b2f(vv.x);
    acc.y = acc.y * scl + pw * b2f(vv.y);
    acc.z = acc.z * scl + pw * b2f(vv.z);
    acc.w = acc.w * scl + pw * b2f(vv.w);
    lsum = lsum * scl + pw;
    m = nm;
  }
  float inv = 1.f / (lsum + 1e-9f);
  float4 fs = *(const float4*)(feats_sem + (size_t)node * 256 + c0);
  ushort4 r;
  r.x = f2bf(acc.x * inv + fs.x);
  r.y = f2bf(acc.y * inv + fs.y);
  r.z = f2bf(acc.z * inv + fs.z);
  r.w = f2bf(acc.w * inv + fs.w);
  *(ushort4*)(agg + (size_t)node * 256 + c0) = r;
}

__global__ void k_bnstats(const ushort* __restrict__ agg, double* __restrict__ colsum,
                          double* __restrict__ colssq) {
  int t = threadIdx.x;
  int r0 = blockIdx.x * 79;
  int r1 = min(r0 + 79, N_NODES);
  double s = 0.0, qq = 0.0;
  for (int r = r0; r < r1; ++r) {
    float x = b2f(agg[(size_t)r * 256 + t]);
    s += (double)x;
    qq += (double)x * (double)x;
  }
  atomicAdd(&colsum[t], s);
  atomicAdd(&colssq[t], qq);
}

__global__ void k_bnfinal(const double* __restrict__ colsum, const double* __restrict__ colssq,
                          float* __restrict__ muArr, float* __restrict__ invArr) {
  int t = threadIdx.x;
  double mu = colsum[t] / (double)N_NODES;
  double var = colssq[t] / (double)N_NODES - mu * mu;
  muArr[t] = (float)mu;
  invArr[t] = (float)(1.0 / sqrt(var + 1e-5));
}

__global__ __launch_bounds__(256) void k_final(const ushort* __restrict__ agg,
                                               const float* __restrict__ muArr,
                                               const float* __restrict__ invArr,
                                               const float* __restrict__ bn_gamma,
                                               const float* __restrict__ bn_beta,
                                               const float* __restrict__ Wout,
                                               const float* __restrict__ bout,
                                               const float* __restrict__ hB,
                                               const float* __restrict__ cent,
                                               const float* __restrict__ gamma,
                                               const float* __restrict__ beta,
                                               float* __restrict__ out) {
  int node = blockIdx.x * 4 + (threadIdx.x >> 6);
  int lane = threadIdx.x & 63;
  int c0 = lane * 4;
  ushort4 xa = *(const ushort4*)(agg + (size_t)node * 256 + c0);
  float4 mu = *(const float4*)(muArr + c0);
  float4 iv = *(const float4*)(invArr + c0);
  float4 g = *(const float4*)(bn_gamma + c0);
  float4 b = *(const float4*)(bn_beta + c0);
  float4 w = *(const float4*)(Wout + c0);
  float p = fmaxf((b2f(xa.x) - mu.x) * iv.x * g.x + b.x, 0.f) * w.x +
            fmaxf((b2f(xa.y) - mu.y) * iv.y * g.y + b.y, 0.f) * w.y +
            fmaxf((b2f(xa.z) - mu.z) * iv.z * g.z + b.z, 0.f) * w.z +
            fmaxf((b2f(xa.w) - mu.w) * iv.w * g.w + b.w, 0.f) * w.w;
  #pragma unroll
  for (int o = 1; o < 64; o <<= 1) p += __shfl_xor(p, o);
  float ls = p + bout[0];
  int h = lane & 7;
  float logit = 0.5f * hB[(size_t)node * 8 + h] + 0.5f * ls;
  float sc = (cent[node] * gamma[h] + beta[h]) * logit;
  sc += __shfl_xor(sc, 1);
  sc += __shfl_xor(sc, 2);
  sc += __shfl_xor(sc, 4);
  float mn = sc * 0.125f;
  mn = (mn >= 0.f) ? mn : 0.01f * mn;
  if (lane == 0) out[node] = mn;
}

// ---------------- launch ----------------

extern "C" void kernel_launch(void* const* d_in, const int* in_sizes, int n_in,
                              void* d_out, int out_size, void* d_ws, size_t ws_size,
                              hipStream_t stream) {
  (void)in_sizes; (void)n_in; (void)out_size; (void)ws_size;
  const float* feats_struct = (const float*)d_in[0];
  const float* feats_sem    = (const float*)d_in[1];
  const float* cent         = (const float*)d_in[2];
  const float* Ws1          = (const float*)d_in[3];
  const float* bs1          = (const float*)d_in[4];
  const float* Ws2          = (const float*)d_in[5];
  const float* bs2          = (const float*)d_in[6];
  const float* rel_emb      = (const float*)d_in[7];
  const float* sa_w         = (const float*)d_in[8];
  const float* sa_al        = (const float*)d_in[9];
  const float* sa_ar        = (const float*)d_in[10];
  const float* sa_We        = (const float*)d_in[11];
  const float* Wq           = (const float*)d_in[12];
  const float* bq           = (const float*)d_in[13];
  const float* Wk           = (const float*)d_in[14];
  const float* bk           = (const float*)d_in[15];
  const float* Wv           = (const float*)d_in[16];
  const float* bv           = (const float*)d_in[17];
  const float* We_gt        = (const float*)d_in[18];
  const float* bn_gamma     = (const float*)d_in[19];
  const float* bn_beta      = (const float*)d_in[20];
  const float* Wout         = (const float*)d_in[21];
  const float* bout         = (const float*)d_in[22];
  const float* gamma        = (const float*)d_in[23];
  const float* beta         = (const float*)d_in[24];
  const int* e_type         = (const int*)d_in[25];
  const int* e_src          = (const int*)d_in[26];
  const int* e_dst          = (const int*)d_in[27];
  float* out = (float*)d_out;

  char* wsb = (char*)d_ws;
  size_t off = 0;
  auto alloc = [&](size_t bytes) -> char* {
    char* p = wsb + off;
    off = (off + bytes + 255) & ~(size_t)255;
    return p;
  };
  float* saTab   = (float*)alloc(2 * 16 * 8 * 4);
  float* epTab   = (float*)alloc(16 * 256 * 4);
  int* deg       = (int*)alloc((size_t)N_NODES * 4);
  int* rowPtr    = (int*)alloc((size_t)(N_NODES + 1) * 4);
  int* cursor    = (int*)alloc((size_t)N_NODES * 4);
  int2* csrPack  = (int2*)alloc((size_t)N_EDGES * 8);
  float* h0      = (float*)alloc((size_t)N_NODES * 8 * 4);
  float* hA      = (float*)alloc((size_t)N_NODES * 8 * 4);
  float* hB      = (float*)alloc((size_t)N_NODES * 8 * 4);
  float* qb      = (float*)alloc((size_t)N_NODES * 256 * 4);
  ushort* kvB    = (ushort*)alloc((size_t)N_NODES * 512 * 2);
  ushort* agg    = (ushort*)alloc((size_t)N_NODES * 256 * 2);
  double* colsum = (double*)alloc(256 * 8);
  double* colssq = (double*)alloc(256 * 8);
  float* muArr   = (float*)alloc(256 * 4);
  float* invArr  = (float*)alloc(256 * 4);
  ushort* Xsb    = (ushort*)alloc((size_t)N_NODES * 256 * 2);
  ushort* Xmb    = (ushort*)alloc((size_t)N_NODES * 256 * 2);
  ushort* Ws1t   = (ushort*)alloc((size_t)8 * 128 * 256 * 2);
  ushort* Wqkvt  = (ushort*)alloc((size_t)3 * 256 * 256 * 2);

  hipMemsetAsync(deg, 0, (size_t)N_NODES * 4, stream);
  hipMemsetAsync(colsum, 0, 256 * 8, stream);
  hipMemsetAsync(colssq, 0, 256 * 8, stream);

  k_setup<<<7793, 256, 0, stream>>>(rel_emb, sa_We, We_gt, feats_struct, feats_sem,
                                    Ws1, Wq, Wk, Wv, e_dst,
                                    saTab, epTab, Xsb, Xmb, Ws1t, Wqkvt, deg);
  k_scan<<<1, 1024, 0, stream>>>(deg, rowPtr, cursor);
  k_fill<<<(N_EDGES + 255) / 256, 256, 0, stream>>>(e_dst, e_src, e_type, cursor, csrPack);

  const int MT = (N_NODES + 127) / 128;  // 157
  dim3 gGemm(MT, 14);
  k_gemm<<<gGemm, 256, 0, stream>>>(Xsb, Xmb, Ws1t, Wqkvt, bs1, Ws2, bs2,
                                    bq, bk, bv, h0, qb, kvB);
  k_sa<<<(N_NODES + 3) / 4, 256, 0, stream>>>(h0, hA, rowPtr, csrPack,
                                              sa_w, sa_al, sa_ar, saTab, 0);
  k_sa<<<(N_NODES + 3) / 4, 256, 0, stream>>>(hA, hB, rowPtr, csrPack,
                                              sa_w, sa_al, sa_ar, saTab, 1);
  k_gt<<<N_NODES / 4, 256, 0, stream>>>(qb, kvB, epTab, feats_sem,
                                        rowPtr, csrPack, agg);
  k_bnstats<<<256, 256, 0, stream>>>(agg, colsum, colssq);
  k_bnfinal<<<1, 256, 0, stream>>>(colsum, colssq, muArr, invArr);
  k_final<<<N_NODES / 4, 256, 0, stream>>>(agg, muArr, invArr, bn_gamma, bn_beta,
                                           Wout, bout, hB, cent, gamma, beta, out);
}